// Round 7
// baseline (279.304 us; speedup 1.0000x reference)
//
#include <hip/hip_runtime.h>
#include <math.h>

#define S_LEN  1024
#define EMB    2048
#define NH_    8
#define DH_    256
#define TOKENS 2048   // B*S
#define NBH    16     // B*NH
#define NQKVO  4608   // 2048 q | 256 k | 256 v | 2048 o

typedef __attribute__((ext_vector_type(4))) float    f32x4;
typedef __attribute__((ext_vector_type(8))) _Float16 f16x8;
typedef __attribute__((ext_vector_type(4))) _Float16 f16x4;

__device__ __forceinline__ _Float16 f2h(float f) { return (_Float16)f; }

// async global->LDS, 16B per lane; LDS dest = wave-uniform base + lane*16
__device__ __forceinline__ void gload16(const void* g, void* l) {
  __builtin_amdgcn_global_load_lds(
      (const __attribute__((address_space(1))) void*)g,
      (__attribute__((address_space(3))) void*)l, 16, 0, 0);
}

// ---------------------------------------------------------------------------
// f32->f16 cast, 8 elems/thread
// ---------------------------------------------------------------------------
__global__ __launch_bounds__(256) void cast_f16_kernel(
    const float* __restrict__ in, _Float16* __restrict__ out, long n)
{
  const long i = ((long)blockIdx.x * 256 + threadIdx.x) * 8;
  if (i >= n) return;
  const float4 a = *(const float4*)(in + i);
  const float4 b = *(const float4*)(in + i + 4);
  f16x8 o = {f2h(a.x), f2h(a.y), f2h(a.z), f2h(a.w),
             f2h(b.x), f2h(b.y), f2h(b.z), f2h(b.w)};
  *(f16x8*)(out + i) = o;
}

// ---------------------------------------------------------------------------
// Tiled transpose + cast to f16: out[z*sOut + c*ldo + r] = in[z*sIn + r*ldi + c]
// ---------------------------------------------------------------------------
template<typename TIN>
__global__ __launch_bounds__(256) void transpose_cast_kernel(
    const TIN* __restrict__ in, long ldi, _Float16* __restrict__ out, long ldo,
    long sIn, long sOut)
{
  __shared__ float t[64][65];
  const int lx = threadIdx.x & 63, ly = threadIdx.x >> 6;
  const long r0 = (long)blockIdx.y * 64, c0 = (long)blockIdx.x * 64;
  const TIN* ip = in + (long)blockIdx.z * sIn;
  _Float16* op = out + (long)blockIdx.z * sOut;
  #pragma unroll
  for (int i = 0; i < 16; ++i)
    t[ly + i * 4][lx] = (float)ip[(r0 + ly + i * 4) * ldi + c0 + lx];
  __syncthreads();
  #pragma unroll
  for (int i = 0; i < 16; ++i)
    op[(c0 + ly + i * 4) * ldo + r0 + lx] = f2h(t[lx][ly + i * 4]);
}

// ---------------------------------------------------------------------------
// f16 GEMM, both operands K-contiguous: C[M,N] = A[M,K] @ Bt[N,K]^T.
// BMx128 tile (BM=128 or 256), BK=32, 4 waves (2x2), wave-tile (BM/2)x64.
// 3-deep prefetch, counted vmcnt; XOR-swizzled LDS (source+read involution,
// verified conflict-free R6).  BM=256 raises FLOP/LDS-byte 32->43.7 (the
// R6-measured LDS-read-BW limit).  Flat grid + bijective XCD swizzle.
// ---------------------------------------------------------------------------
template<typename CT, int BM>
__global__ __launch_bounds__(256) void gemm_bt_kernel(
    const _Float16* __restrict__ Ag, const _Float16* __restrict__ Btg,
    CT* __restrict__ Cg, int K, int lda, int ldb, int ldc,
    long sA, long sB, long sC, int zdivB, int mtiles, int causal)
{
  constexpr int MR = BM / 32;                 // m-fragments per wave (4 or 8)
  __shared__ _Float16 As[3][BM * 32];
  __shared__ _Float16 Bs[3][128 * 32];
  const int tid = threadIdx.x;
  const int lane = tid & 63, wid = tid >> 6;
  // XCD-bijective swizzle (gridDim.x % 8 == 0)
  const int cpx = gridDim.x >> 3;
  const int wg = ((int)blockIdx.x & 7) * cpx + ((int)blockIdx.x >> 3);
  const int m0 = (wg % mtiles) * BM;
  const int n0 = (wg / mtiles) * 128;
  const int z  = blockIdx.z;
  const _Float16* Ap = Ag + (long)z * sA + (long)m0 * lda;
  const _Float16* Bp = Btg + (long)(z / zdivB) * sB + (long)n0 * ldb;
  const int wr = wid >> 1, wc = wid & 1;
  const int lrow = lane & 15, kseg = lane >> 4;
  const int kl = causal ? ((m0 + BM < K) ? m0 + BM : K) : K;

  auto stage = [&](int b, int k0) {
    #pragma unroll
    for (int i = 0; i < BM / 64; ++i) {       // A: BM*4 chunks
      const int cbase = (i * 4 + wid) * 64;
      const int row = (cbase >> 2) + (lane >> 2);
      const int src = ((lane & 3) ^ ((row >> 1) & 3)) * 8;
      gload16(Ap + (long)row * lda + k0 + src, (char*)As[b] + cbase * 16);
    }
    #pragma unroll
    for (int i = 0; i < 2; ++i) {             // B: 512 chunks
      const int cbase = (i * 4 + wid) * 64;
      const int row = (cbase >> 2) + (lane >> 2);
      const int src = ((lane & 3) ^ ((row >> 1) & 3)) * 8;
      gload16(Bp + (long)row * ldb + k0 + src, (char*)Bs[b] + cbase * 16);
    }
  };

  const int nt = kl >> 5;                     // K-tiles of 32
  f32x4 acc[MR][4] = {};
  stage(0, 0);
  if (nt > 1) stage(1, 32);
  for (int t = 0; t < nt; ++t) {
    if (t + 2 < nt) {
      stage((t + 2) % 3, (t + 2) * 32);
      if constexpr (BM == 256) asm volatile("s_waitcnt vmcnt(12)" ::: "memory");
      else                     asm volatile("s_waitcnt vmcnt(8)"  ::: "memory");
    } else if (t + 1 < nt) {
      if constexpr (BM == 256) asm volatile("s_waitcnt vmcnt(6)" ::: "memory");
      else                     asm volatile("s_waitcnt vmcnt(4)" ::: "memory");
    } else {
      asm volatile("s_waitcnt vmcnt(0)" ::: "memory");
    }
    __builtin_amdgcn_s_barrier();
    __builtin_amdgcn_sched_barrier(0);
    const int buf = t % 3;
    f16x8 fa[MR], fb[4];
    #pragma unroll
    for (int m = 0; m < MR; ++m) {
      const int row = wr * (BM / 2) + m * 16 + lrow;
      fa[m] = *(const f16x8*)&As[buf][row * 32 + ((kseg ^ ((row >> 1) & 3)) << 3)];
    }
    #pragma unroll
    for (int n = 0; n < 4; ++n) {
      const int row = wc * 64 + n * 16 + lrow;
      fb[n] = *(const f16x8*)&Bs[buf][row * 32 + ((kseg ^ ((row >> 1) & 3)) << 3)];
    }
    #pragma unroll
    for (int m = 0; m < MR; ++m)
      #pragma unroll
      for (int n = 0; n < 4; ++n)
        acc[m][n] = __builtin_amdgcn_mfma_f32_16x16x32_f16(fa[m], fb[n], acc[m][n], 0, 0, 0);
    __builtin_amdgcn_s_barrier();             // reads done before overwrite
  }
  CT* Cp = Cg + (long)z * sC;
  #pragma unroll
  for (int m = 0; m < MR; ++m)
    #pragma unroll
    for (int n = 0; n < 4; ++n)
      #pragma unroll
      for (int i = 0; i < 4; ++i) {
        const int r = m0 + wr * (BM / 2) + m * 16 + kseg * 4 + i;  // row=(lane>>4)*4+i (m89)
        const int c = n0 + wc * 64 + n * 16 + lrow;                // col=lane&15
        Cp[(long)r * ldc + c] = (CT)acc[m][n][i];
      }
}

// ---------------------------------------------------------------------------
// i/f gate projections: per token, 16 dot products over E=2048, soft-capped.
// ---------------------------------------------------------------------------
__global__ __launch_bounds__(256) void proj_if_kernel(
    const float* __restrict__ x, const float* __restrict__ Wi, const float* __restrict__ bi,
    const float* __restrict__ Wf, const float* __restrict__ bfg,
    float* __restrict__ ip, float* __restrict__ fp)
{
  const int tok = blockIdx.x;
  const int tid = threadIdx.x;
  const float* xr = x + (long)tok * EMB;
  float ai[8] = {}, af[8] = {};
  #pragma unroll
  for (int j = 0; j < 8; ++j) {
    const int e = tid + j * 256;
    const float xe = xr[e];
    const float4* wi4 = (const float4*)(Wi + (long)e * 8);
    const float4* wf4 = (const float4*)(Wf + (long)e * 8);
    const float4 a0 = wi4[0], a1 = wi4[1], b0 = wf4[0], b1 = wf4[1];
    ai[0] += xe * a0.x; ai[1] += xe * a0.y; ai[2] += xe * a0.z; ai[3] += xe * a0.w;
    ai[4] += xe * a1.x; ai[5] += xe * a1.y; ai[6] += xe * a1.z; ai[7] += xe * a1.w;
    af[0] += xe * b0.x; af[1] += xe * b0.y; af[2] += xe * b0.z; af[3] += xe * b0.w;
    af[4] += xe * b1.x; af[5] += xe * b1.y; af[6] += xe * b1.z; af[7] += xe * b1.w;
  }
  #pragma unroll
  for (int hh = 0; hh < 8; ++hh)
    for (int off = 32; off; off >>= 1) {
      ai[hh] += __shfl_xor(ai[hh], off);
      af[hh] += __shfl_xor(af[hh], off);
    }
  __shared__ float red[4][16];
  const int lane = tid & 63, wid = tid >> 6;
  if (lane == 0) {
    #pragma unroll
    for (int hh = 0; hh < 8; ++hh) { red[wid][hh] = ai[hh]; red[wid][hh + 8] = af[hh]; }
  }
  __syncthreads();
  if (tid < 16) {
    const float v = red[0][tid] + red[1][tid] + red[2][tid] + red[3][tid];
    const int b = tok >> 10, s = tok & 1023;
    if (tid < 8) {
      const float zv = v + bi[tid];
      ip[(long)(b * NH_ + tid) * S_LEN + s] = 15.0f * tanhf(zv * (1.0f / 15.0f));
    } else {
      const int hh = tid - 8;
      const float zv = v + bfg[hh];
      fp[(long)(b * NH_ + hh) * S_LEN + s] = 15.0f * tanhf(zv * (1.0f / 15.0f));
    }
  }
}

// ---------------------------------------------------------------------------
// Per (b,h): logsigmoid, cumsum cf, a = i_pre - cf, running max m, vecM = cf+m.
// ---------------------------------------------------------------------------
__global__ __launch_bounds__(1024) void gates_kernel(
    const float* __restrict__ fp, const float* __restrict__ ip,
    float* __restrict__ aArr, float* __restrict__ mArr, float* __restrict__ vMArr)
{
  const int bh = blockIdx.x;
  const int s = threadIdx.x;
  __shared__ float sh[1024];
  const float f = fp[(long)bh * S_LEN + s];
  const float lsg = fminf(f, 0.0f) - log1pf(expf(-fabsf(f)));  // log_sigmoid
  float v = lsg;
  sh[s] = v; __syncthreads();
  for (int off = 1; off < 1024; off <<= 1) {
    const float o = (s >= off) ? sh[s - off] : 0.0f;
    __syncthreads();
    v += o; sh[s] = v;
    __syncthreads();
  }
  const float cf = v;
  const float a = ip[(long)bh * S_LEN + s] - cf;
  v = a;
  sh[s] = v; __syncthreads();
  for (int off = 1; off < 1024; off <<= 1) {
    const float o = (s >= off) ? sh[s - off] : -3.0e38f;
    __syncthreads();
    v = fmaxf(v, o); sh[s] = v;
    __syncthreads();
  }
  aArr[(long)bh * S_LEN + s] = a;
  mArr[(long)bh * S_LEN + s] = v;
  vMArr[(long)bh * S_LEN + s] = cf + v;
}

// ---------------------------------------------------------------------------
// Fused mLSTM attention, triangle-paired for causal load balance.
// Block (i, bh) owns q-subtiles qi=i and qi=31-i (32 rows each) => every
// block does exactly 9 subtile-passes.  T5: setprio around MFMA clusters.
// ---------------------------------------------------------------------------
__global__ __launch_bounds__(256) void att_fused_kernel(
    const _Float16* __restrict__ qkvo, const _Float16* __restrict__ vt,
    const float* __restrict__ aArr, const float* __restrict__ mArr,
    const float* __restrict__ vMArr, _Float16* __restrict__ hb)
{
  __shared__ _Float16 Qs[2][32 * 256];   // swizzled: 32 chunks/row, ^(row&7)
  __shared__ _Float16 Ws[2][32 * 128];   // swizzled: 16 chunks/row, ^((row&7)<<1)
  __shared__ float nsh[2][4][32];
  __shared__ float invs[2][32];
  const int tid = threadIdx.x;
  const int lane = tid & 63, wid = tid >> 6;
  const int bh = blockIdx.y;
  const int b = bh >> 3, h = bh & 7;
  const int r0[2] = { (int)blockIdx.x * 32, (31 - (int)blockIdx.x) * 32 };
  const _Float16* Qg = qkvo + (long)(b * S_LEN) * NQKVO + h * DH_;
  const _Float16* Kg = qkvo + (long)(b * S_LEN) * NQKVO + 2048;
  const _Float16* Vt = vt + (long)b * DH_ * S_LEN;
  const float* aA = aArr + (long)bh * S_LEN;
  const float* mA = mArr + (long)bh * S_LEN;
  const int lrow = lane & 15, kseg = lane >> 4;
  const int tbase = 32 * wid;

  #pragma unroll
  for (int i = 0; i < 8; ++i) {
    const int cbase = (i * 4 + wid) * 64;   // wave-uniform; sub uniform per iter
    const int c = cbase + lane;
    const int sub = c >> 10, row = (c >> 5) & 31, slot = c & 31;
    gload16(Qg + (long)(r0[sub] + row) * NQKVO + (slot ^ (row & 7)) * 8,
            (char*)Qs + cbase * 16);
  }

  float m_s[2][2][4];
  #pragma unroll
  for (int sub = 0; sub < 2; ++sub)
    #pragma unroll
    for (int m = 0; m < 2; ++m)
      #pragma unroll
      for (int i = 0; i < 4; ++i)
        m_s[sub][m][i] = mA[r0[sub] + m * 16 + kseg * 4 + i];
  __syncthreads();   // Q staged (drains vmcnt)

  f32x4 hacc[2][2][4] = {};
  float nacc[2][2][4] = {};
  for (int n0 = 0; n0 <= r0[1]; n0 += 128) {
    // ---- QK^T: K frags global->reg, shared across subtiles ----
    f32x4 acc[2][2][2] = {};
    for (int k0 = 0; k0 < DH_; k0 += 32) {
      f16x8 fb[2];
      #pragma unroll
      for (int n = 0; n < 2; ++n)
        fb[n] = *(const f16x8*)(Kg + (long)(n0 + tbase + n * 16 + lrow) * NQKVO + k0 + kseg * 8);
      const int chunk = (k0 >> 3) + kseg;
      __builtin_amdgcn_s_setprio(1);
      #pragma unroll
      for (int sub = 0; sub < 2; ++sub) {
        if (n0 > r0[sub]) continue;
        #pragma unroll
        for (int m = 0; m < 2; ++m) {
          const int qrow = m * 16 + lrow;
          const f16x8 fa = *(const f16x8*)&Qs[sub][qrow * 256 + ((chunk ^ (qrow & 7)) << 3)];
          #pragma unroll
          for (int n = 0; n < 2; ++n)
            acc[sub][m][n] = __builtin_amdgcn_mfma_f32_16x16x32_f16(fa, fb[n], acc[sub][m][n], 0, 0, 0);
        }
      }
      __builtin_amdgcn_s_setprio(0);
    }
    // ---- weighting -> Ws (swizzled), row-sum accumulation ----
    float a_t[2];
    #pragma unroll
    for (int n = 0; n < 2; ++n) a_t[n] = aA[n0 + tbase + n * 16 + lrow];
    #pragma unroll
    for (int sub = 0; sub < 2; ++sub) {
      if (n0 > r0[sub]) continue;
      #pragma unroll
      for (int m = 0; m < 2; ++m)
        #pragma unroll
        for (int n = 0; n < 2; ++n)
          #pragma unroll
          for (int i = 0; i < 4; ++i) {
            const int sr = m * 16 + kseg * 4 + i;       // local row 0..31
            const int t  = tbase + n * 16 + lrow;       // local col 0..127
            float w = 0.0f;
            if (n0 + t <= r0[sub] + sr)
              w = acc[sub][m][n][i] * 0.0625f * expf(a_t[n] - m_s[sub][m][i]);
            nacc[sub][m][i] += w;
            Ws[sub][sr * 128 + (((t >> 3) ^ ((sr & 7) << 1)) << 3) + (t & 7)] = f2h(w);
          }
    }
    __syncthreads();
    // ---- PV: V frags global->reg (shared), Ws from LDS ----
    for (int kt = 0; kt < 128; kt += 32) {
      f16x8 vb[4];
      #pragma unroll
      for (int n = 0; n < 4; ++n)
        vb[n] = *(const f16x8*)(Vt + (long)(64 * wid + n * 16 + lrow) * S_LEN + n0 + kt + kseg * 8);
      const int chunk = (kt >> 3) + kseg;
      __builtin_amdgcn_s_setprio(1);
      #pragma unroll
      for (int sub = 0; sub < 2; ++sub) {
        if (n0 > r0[sub]) continue;
        #pragma unroll
        for (int m = 0; m < 2; ++m) {
          const int row = m * 16 + lrow;
          const f16x8 wa = *(const f16x8*)&Ws[sub][row * 128 + ((chunk ^ ((row & 7) << 1)) << 3)];
          #pragma unroll
          for (int n = 0; n < 4; ++n)
            hacc[sub][m][n] = __builtin_amdgcn_mfma_f32_16x16x32_f16(wa, vb[n], hacc[sub][m][n], 0, 0, 0);
        }
      }
      __builtin_amdgcn_s_setprio(0);
    }
    __syncthreads();   // Ws reads done before next pass overwrites
  }
  // ---- row sums -> invn ----
  #pragma unroll
  for (int sub = 0; sub < 2; ++sub)
    #pragma unroll
    for (int m = 0; m < 2; ++m)
      #pragma unroll
      for (int i = 0; i < 4; ++i) {
        float v = nacc[sub][m][i];
        v += __shfl_xor(v, 1); v += __shfl_xor(v, 2);
        v += __shfl_xor(v, 4); v += __shfl_xor(v, 8);
        if (lrow == 0) nsh[sub][wid][m * 16 + kseg * 4 + i] = v;
      }
  __syncthreads();
  if (tid < 64) {
    const int sub = tid >> 5, sr = tid & 31;
    const float tot = nsh[sub][0][sr] + nsh[sub][1][sr] + nsh[sub][2][sr] + nsh[sub][3][sr];
    const float vm = vMArr[(long)bh * S_LEN + r0[sub] + sr];
    const float vecN = fmaxf(fabsf(tot), expf(-vm));
    invs[sub][sr] = 1.0f / (vecN + 1e-6f);
  }
  __syncthreads();
  #pragma unroll
  for (int sub = 0; sub < 2; ++sub)
    #pragma unroll
    for (int m = 0; m < 2; ++m)
      #pragma unroll
      for (int n = 0; n < 4; ++n)
        #pragma unroll
        for (int i = 0; i < 4; ++i) {
          const int row = m * 16 + kseg * 4 + i;
          const int d = 64 * wid + n * 16 + lrow;
          hb[((long)bh * S_LEN + r0[sub] + row) * DH_ + d] = f2h(hacc[sub][m][n][i] * invs[sub][row]);
        }
}

// ---------------------------------------------------------------------------
// One wave per (token, head) row: LN over DH=256 (f32), *gamma, *sigmoid(o).
// ---------------------------------------------------------------------------
__global__ __launch_bounds__(256) void ln_gate_kernel(
    const _Float16* __restrict__ hbuf,
    const _Float16* __restrict__ qkvo, const float* __restrict__ gamma,
    _Float16* __restrict__ u)
{
  const int wid = threadIdx.x >> 6, lane = threadIdx.x & 63;
  const int row = blockIdx.x * 4 + wid;   // row = tok*8 + h
  const int tok = row >> 3, h = row & 7;
  const int b = tok >> 10, s = tok & 1023;
  const int bh = b * NH_ + h;
  const f16x4 hv = *(const f16x4*)(hbuf + ((long)bh * S_LEN + s) * DH_ + lane * 4);
  const float v0 = (float)hv[0], v1 = (float)hv[1], v2 = (float)hv[2], v3 = (float)hv[3];
  float s1 = v0 + v1 + v2 + v3;
  float s2 = v0 * v0 + v1 * v1 + v2 * v2 + v3 * v3;
  for (int off = 32; off; off >>= 1) { s1 += __shfl_xor(s1, off); s2 += __shfl_xor(s2, off); }
  const float mu = s1 * (1.0f / 256.0f);
  const float var = s2 * (1.0f / 256.0f) - mu * mu;
  const float rs = rsqrtf(var + 1e-6f);
  const float4 g = *(const float4*)(gamma + h * DH_ + lane * 4);
  const f16x4 ov = *(const f16x4*)(qkvo + (long)tok * NQKVO + 2560 + h * DH_ + lane * 4);
  f16x4 res;
  res[0] = f2h((v0 - mu) * rs * g.x * (1.0f / (1.0f + expf(-(float)ov[0]))));
  res[1] = f2h((v1 - mu) * rs * g.y * (1.0f / (1.0f + expf(-(float)ov[1]))));
  res[2] = f2h((v2 - mu) * rs * g.z * (1.0f / (1.0f + expf(-(float)ov[2]))));
  res[3] = f2h((v3 - mu) * rs * g.w * (1.0f / (1.0f + expf(-(float)ov[3]))));
  *(f16x4*)(u + (long)tok * EMB + h * DH_ + lane * 4) = res;
}

// ---------------------------------------------------------------------------
extern "C" void kernel_launch(void* const* d_in, const int* in_sizes, int n_in,
                              void* d_out, int out_size, void* d_ws, size_t ws_size,
                              hipStream_t stream)
{
  (void)in_sizes; (void)n_in; (void)out_size; (void)ws_size;
  const float* x     = (const float*)d_in[0];
  const float* Wq    = (const float*)d_in[1];
  const float* Wk    = (const float*)d_in[2];
  const float* Wv    = (const float*)d_in[3];
  const float* Wog   = (const float*)d_in[4];
  const float* Wi    = (const float*)d_in[5];
  const float* bi    = (const float*)d_in[6];
  const float* Wf    = (const float*)d_in[7];
  const float* bfg   = (const float*)d_in[8];
  const float* gamma = (const float*)d_in[9];
  const float* Wout  = (const float*)d_in[10];

  char* base = (char*)d_ws;
  size_t off = 0;
  auto take = [&](size_t bytes) -> char* {
    char* p = base + off;
    off += (bytes + 255) & ~(size_t)255;
    return p;
  };
  _Float16* xh    = (_Float16*)take((size_t)TOKENS * EMB * 2);        //  8 MB
  _Float16* WcatT = (_Float16*)take((size_t)NQKVO * EMB * 2);         // 19 MB
  _Float16* WoutT = (_Float16*)take((size_t)EMB * EMB * 2);           //  8 MB
  _Float16* qkvo  = (_Float16*)take((size_t)TOKENS * NQKVO * 2);      // 19 MB
  _Float16* vt    = (_Float16*)take((size_t)2 * DH_ * S_LEN * 2);     //  1 MB
  _Float16* hb    = (_Float16*)take((size_t)NBH * S_LEN * DH_ * 2);   //  8 MB
  float*    ip    = (float*)take((size_t)NBH * S_LEN * 4);
  float*    fp    = (float*)take((size_t)NBH * S_LEN * 4);
  float*    aA    = (float*)take((size_t)NBH * S_LEN * 4);
  float*    mA    = (float*)take((size_t)NBH * S_LEN * 4);
  float*    vM    = (float*)take((size_t)NBH * S_LEN * 4);
  _Float16* ub    = xh;   // xh dead after QKVO GEMM
  float*    y     = (float*)d_out;

  const dim3 blk(256);
  // --- one-time casts / transposes ---
  cast_f16_kernel<<<dim3((TOKENS * EMB) / (256 * 8)), blk, 0, stream>>>(x, xh, (long)TOKENS * EMB);
  transpose_cast_kernel<float><<<dim3(32, 32), blk, 0, stream>>>(Wq,   EMB, WcatT,                     EMB, 0L, 0L);
  transpose_cast_kernel<float><<<dim3( 4, 32), blk, 0, stream>>>(Wk,   DH_, WcatT + (long)2048 * EMB,  EMB, 0L, 0L);
  transpose_cast_kernel<float><<<dim3( 4, 32), blk, 0, stream>>>(Wv,   DH_, WcatT + (long)2304 * EMB,  EMB, 0L, 0L);
  transpose_cast_kernel<float><<<dim3(32, 32), blk, 0, stream>>>(Wog,  EMB, WcatT + (long)2560 * EMB,  EMB, 0L, 0L);
  transpose_cast_kernel<float><<<dim3(32, 32), blk, 0, stream>>>(Wout, EMB, WoutT,                     EMB, 0L, 0L);
  // --- fused QKVO projection: [2048,4608] = xh @ WcatT^T (8 m-tiles x 36 n-tiles) ---
  gemm_bt_kernel<_Float16, 256><<<dim3(8 * 36), blk, 0, stream>>>(
      xh, WcatT, qkvo, EMB, EMB, EMB, NQKVO, 0L, 0L, 0L, 1, 8, 0);
  // --- V^T per batch ---
  transpose_cast_kernel<_Float16><<<dim3(4, 16, 2), blk, 0, stream>>>(
      qkvo + 2304, NQKVO, vt, S_LEN, (long)S_LEN * NQKVO, (long)DH_ * S_LEN);
  // --- gates ---
  proj_if_kernel<<<dim3(TOKENS), blk, 0, stream>>>(x, Wi, bi, Wf, bfg, ip, fp);
  gates_kernel<<<dim3(NBH), dim3(1024), 0, stream>>>(fp, ip, aA, mA, vM);
  // --- fused mLSTM backend (triangle-paired, K/V direct-from-global) ---
  att_fused_kernel<<<dim3(16, NBH), blk, 0, stream>>>(qkvo, vt, aA, mA, vM, hb);
  // --- layernorm + output gate ---
  ln_gate_kernel<<<dim3(TOKENS * NH_ / 4), blk, 0, stream>>>(hb, qkvo, gamma, ub);
  // --- output projection (16 m-tiles x 16 n-tiles, BM=128) ---
  gemm_bt_kernel<float, 128><<<dim3(16 * 16), blk, 0, stream>>>(
      ub, WoutT, y, EMB, EMB, EMB, EMB, 0L, 0L, 0L, 1, 16, 0);
}

// Round 8
// 216.609 us; speedup vs baseline: 1.2894x; 1.2894x over previous
//
#include <hip/hip_runtime.h>
#include <math.h>

#define S_LEN  1024
#define EMB    2048
#define NH_    8
#define DH_    256
#define TOKENS 2048   // B*S
#define NBH    16     // B*NH
#define NQKVO  4608   // 2048 q | 256 k | 256 v | 2048 o

typedef __attribute__((ext_vector_type(4))) float    f32x4;
typedef __attribute__((ext_vector_type(8))) _Float16 f16x8;
typedef __attribute__((ext_vector_type(4))) _Float16 f16x4;

__device__ __forceinline__ _Float16 f2h(float f) { return (_Float16)f; }

// async global->LDS, 16B per lane; LDS dest = wave-uniform base + lane*16
__device__ __forceinline__ void gload16(const void* g, void* l) {
  __builtin_amdgcn_global_load_lds(
      (const __attribute__((address_space(1))) void*)g,
      (__attribute__((address_space(3))) void*)l, 16, 0, 0);
}

// ---------------------------------------------------------------------------
// f32->f16 cast, 8 elems/thread
// ---------------------------------------------------------------------------
__global__ __launch_bounds__(256) void cast_f16_kernel(
    const float* __restrict__ in, _Float16* __restrict__ out, long n)
{
  const long i = ((long)blockIdx.x * 256 + threadIdx.x) * 8;
  if (i >= n) return;
  const float4 a = *(const float4*)(in + i);
  const float4 b = *(const float4*)(in + i + 4);
  f16x8 o = {f2h(a.x), f2h(a.y), f2h(a.z), f2h(a.w),
             f2h(b.x), f2h(b.y), f2h(b.z), f2h(b.w)};
  *(f16x8*)(out + i) = o;
}

// ---------------------------------------------------------------------------
// Fused weight transposes (Wq,Wk,Wv,Wog -> WcatT; Wout -> WoutT), one launch.
// All are 2048-row f32 -> f16 transposed, 64x64 tiles.
// ---------------------------------------------------------------------------
__global__ __launch_bounds__(256) void transpose_all_kernel(
    const float* __restrict__ Wq, const float* __restrict__ Wk,
    const float* __restrict__ Wv, const float* __restrict__ Wog,
    const float* __restrict__ Wout,
    _Float16* __restrict__ WcatT, _Float16* __restrict__ WoutT)
{
  int t = blockIdx.x;
  const float* in; _Float16* out; int ldi, ct;
  if (t < 1024)      { in = Wq;   out = WcatT;                    ldi = 2048; ct = 32; }
  else if (t < 1152) { t -= 1024; in = Wk;  out = WcatT + (long)2048 * EMB; ldi = 256; ct = 4; }
  else if (t < 1280) { t -= 1152; in = Wv;  out = WcatT + (long)2304 * EMB; ldi = 256; ct = 4; }
  else if (t < 2304) { t -= 1280; in = Wog; out = WcatT + (long)2560 * EMB; ldi = 2048; ct = 32; }
  else               { t -= 2304; in = Wout; out = WoutT;         ldi = 2048; ct = 32; }
  const long c0 = (long)(t % ct) * 64, r0 = (long)(t / ct) * 64;
  __shared__ float tl[64][65];
  const int lx = threadIdx.x & 63, ly = threadIdx.x >> 6;
  #pragma unroll
  for (int i = 0; i < 16; ++i)
    tl[ly + i * 4][lx] = in[(r0 + ly + i * 4) * ldi + c0 + lx];
  __syncthreads();
  #pragma unroll
  for (int i = 0; i < 16; ++i)
    out[(c0 + ly + i * 4) * EMB + r0 + lx] = f2h(tl[lx][ly + i * 4]);
}

// ---------------------------------------------------------------------------
// Tiled transpose + cast to f16 (f16 input path used for V^T).
// ---------------------------------------------------------------------------
template<typename TIN>
__global__ __launch_bounds__(256) void transpose_cast_kernel(
    const TIN* __restrict__ in, long ldi, _Float16* __restrict__ out, long ldo,
    long sIn, long sOut)
{
  __shared__ float t[64][65];
  const int lx = threadIdx.x & 63, ly = threadIdx.x >> 6;
  const long r0 = (long)blockIdx.y * 64, c0 = (long)blockIdx.x * 64;
  const TIN* ip = in + (long)blockIdx.z * sIn;
  _Float16* op = out + (long)blockIdx.z * sOut;
  #pragma unroll
  for (int i = 0; i < 16; ++i)
    t[ly + i * 4][lx] = (float)ip[(r0 + ly + i * 4) * ldi + c0 + lx];
  __syncthreads();
  #pragma unroll
  for (int i = 0; i < 16; ++i)
    op[(c0 + ly + i * 4) * ldo + r0 + lx] = f2h(t[lx][ly + i * 4]);
}

// ---------------------------------------------------------------------------
// Wide f16 GEMM: C[M,N] = A[M,K] @ Bt[N,K]^T, 128x256 tile, BK=32, 4 waves
// side-by-side along N (wave-tile 128x64 -> 32 MFMA/step/wave, 2x R6's per-
// barrier compute).  2-buf (48KB) + launch_bounds(256,2) keeps 2 blocks/CU
// resident (R7 lesson: acc regs count against the unified file).  XOR-swizzle
// (verified conflict-free R6) + bijective XCD swizzle.
// ---------------------------------------------------------------------------
template<typename CT>
__global__ __launch_bounds__(256, 2) void gemm_wide_kernel(
    const _Float16* __restrict__ Ag, const _Float16* __restrict__ Btg,
    CT* __restrict__ Cg, int K, int lda, int ldb, int ldc, int mtiles)
{
  __shared__ _Float16 As[2][128 * 32];
  __shared__ _Float16 Bs[2][256 * 32];
  const int tid = threadIdx.x;
  const int lane = tid & 63, wid = tid >> 6;
  const int cpx = gridDim.x >> 3;
  const int wg = ((int)blockIdx.x & 7) * cpx + ((int)blockIdx.x >> 3);
  const int m0 = (wg % mtiles) * 128;
  const int n0 = (wg / mtiles) * 256;
  const _Float16* Ap = Ag + (long)m0 * lda;
  const _Float16* Bp = Btg + (long)n0 * ldb;
  const int lrow = lane & 15, kseg = lane >> 4;

  auto stage = [&](int b, int k0) {
    #pragma unroll
    for (int i = 0; i < 2; ++i) {              // A: 512 chunks
      const int cbase = (i * 4 + wid) * 64;
      const int row = (cbase >> 2) + (lane >> 2);
      const int src = ((lane & 3) ^ ((row >> 1) & 3)) * 8;
      gload16(Ap + (long)row * lda + k0 + src, (char*)As[b] + cbase * 16);
    }
    #pragma unroll
    for (int i = 0; i < 4; ++i) {              // B: 1024 chunks
      const int cbase = (i * 4 + wid) * 64;
      const int row = (cbase >> 2) + (lane >> 2);
      const int src = ((lane & 3) ^ ((row >> 1) & 3)) * 8;
      gload16(Bp + (long)row * ldb + k0 + src, (char*)Bs[b] + cbase * 16);
    }
  };

  const int nt = K >> 5;
  f32x4 acc[8][4] = {};
  stage(0, 0);
  int buf = 0;
  for (int t = 0; t < nt; ++t) {
    if (t + 1 < nt) {
      stage(buf ^ 1, (t + 1) * 32);            // prefetch next tile
      asm volatile("s_waitcnt vmcnt(6)" ::: "memory");  // cur's 6 loads done
    } else {
      asm volatile("s_waitcnt vmcnt(0)" ::: "memory");
    }
    __builtin_amdgcn_s_barrier();
    __builtin_amdgcn_sched_barrier(0);
    f16x8 fa[8], fb[4];
    #pragma unroll
    for (int m = 0; m < 8; ++m) {
      const int row = m * 16 + lrow;
      fa[m] = *(const f16x8*)&As[buf][row * 32 + ((kseg ^ ((row >> 1) & 3)) << 3)];
    }
    #pragma unroll
    for (int n = 0; n < 4; ++n) {
      const int row = wid * 64 + n * 16 + lrow;
      fb[n] = *(const f16x8*)&Bs[buf][row * 32 + ((kseg ^ ((row >> 1) & 3)) << 3)];
    }
    #pragma unroll
    for (int m = 0; m < 8; ++m)
      #pragma unroll
      for (int n = 0; n < 4; ++n)
        acc[m][n] = __builtin_amdgcn_mfma_f32_16x16x32_f16(fa[m], fb[n], acc[m][n], 0, 0, 0);
    __builtin_amdgcn_s_barrier();              // reads done before overwrite
    buf ^= 1;
  }
  #pragma unroll
  for (int m = 0; m < 8; ++m)
    #pragma unroll
    for (int n = 0; n < 4; ++n)
      #pragma unroll
      for (int i = 0; i < 4; ++i) {
        const int r = m0 + m * 16 + kseg * 4 + i;        // row=(lane>>4)*4+i (m89)
        const int c = n0 + wid * 64 + n * 16 + lrow;     // col=lane&15
        Cg[(long)r * ldc + c] = (CT)acc[m][n][i];
      }
}

// ---------------------------------------------------------------------------
// f16 GEMM, 128x128 tile, BK=32, 4 waves (2x2), 3-deep prefetch (R6 config,
// known-good for 256-block grids).
// ---------------------------------------------------------------------------
template<typename CT, int BM>
__global__ __launch_bounds__(256) void gemm_bt_kernel(
    const _Float16* __restrict__ Ag, const _Float16* __restrict__ Btg,
    CT* __restrict__ Cg, int K, int lda, int ldb, int ldc,
    long sA, long sB, long sC, int zdivB, int mtiles, int causal)
{
  constexpr int MR = BM / 32;
  __shared__ _Float16 As[3][BM * 32];
  __shared__ _Float16 Bs[3][128 * 32];
  const int tid = threadIdx.x;
  const int lane = tid & 63, wid = tid >> 6;
  const int cpx = gridDim.x >> 3;
  const int wg = ((int)blockIdx.x & 7) * cpx + ((int)blockIdx.x >> 3);
  const int m0 = (wg % mtiles) * BM;
  const int n0 = (wg / mtiles) * 128;
  const int z  = blockIdx.z;
  const _Float16* Ap = Ag + (long)z * sA + (long)m0 * lda;
  const _Float16* Bp = Btg + (long)(z / zdivB) * sB + (long)n0 * ldb;
  const int wr = wid >> 1, wc = wid & 1;
  const int lrow = lane & 15, kseg = lane >> 4;
  const int kl = causal ? ((m0 + BM < K) ? m0 + BM : K) : K;

  auto stage = [&](int b, int k0) {
    #pragma unroll
    for (int i = 0; i < BM / 64; ++i) {
      const int cbase = (i * 4 + wid) * 64;
      const int row = (cbase >> 2) + (lane >> 2);
      const int src = ((lane & 3) ^ ((row >> 1) & 3)) * 8;
      gload16(Ap + (long)row * lda + k0 + src, (char*)As[b] + cbase * 16);
    }
    #pragma unroll
    for (int i = 0; i < 2; ++i) {
      const int cbase = (i * 4 + wid) * 64;
      const int row = (cbase >> 2) + (lane >> 2);
      const int src = ((lane & 3) ^ ((row >> 1) & 3)) * 8;
      gload16(Bp + (long)row * ldb + k0 + src, (char*)Bs[b] + cbase * 16);
    }
  };

  const int nt = kl >> 5;
  f32x4 acc[MR][4] = {};
  stage(0, 0);
  if (nt > 1) stage(1, 32);
  for (int t = 0; t < nt; ++t) {
    if (t + 2 < nt) {
      stage((t + 2) % 3, (t + 2) * 32);
      asm volatile("s_waitcnt vmcnt(8)" ::: "memory");
    } else if (t + 1 < nt) {
      asm volatile("s_waitcnt vmcnt(4)" ::: "memory");
    } else {
      asm volatile("s_waitcnt vmcnt(0)" ::: "memory");
    }
    __builtin_amdgcn_s_barrier();
    __builtin_amdgcn_sched_barrier(0);
    const int buf = t % 3;
    f16x8 fa[MR], fb[4];
    #pragma unroll
    for (int m = 0; m < MR; ++m) {
      const int row = wr * (BM / 2) + m * 16 + lrow;
      fa[m] = *(const f16x8*)&As[buf][row * 32 + ((kseg ^ ((row >> 1) & 3)) << 3)];
    }
    #pragma unroll
    for (int n = 0; n < 4; ++n) {
      const int row = wc * 64 + n * 16 + lrow;
      fb[n] = *(const f16x8*)&Bs[buf][row * 32 + ((kseg ^ ((row >> 1) & 3)) << 3)];
    }
    #pragma unroll
    for (int m = 0; m < MR; ++m)
      #pragma unroll
      for (int n = 0; n < 4; ++n)
        acc[m][n] = __builtin_amdgcn_mfma_f32_16x16x32_f16(fa[m], fb[n], acc[m][n], 0, 0, 0);
    __builtin_amdgcn_s_barrier();
  }
  CT* Cp = Cg + (long)z * sC;
  #pragma unroll
  for (int m = 0; m < MR; ++m)
    #pragma unroll
    for (int n = 0; n < 4; ++n)
      #pragma unroll
      for (int i = 0; i < 4; ++i) {
        const int r = m0 + wr * (BM / 2) + m * 16 + kseg * 4 + i;
        const int c = n0 + wc * 64 + n * 16 + lrow;
        Cp[(long)r * ldc + c] = (CT)acc[m][n][i];
      }
}

// ---------------------------------------------------------------------------
// i/f gate projections: per token, 16 dot products over E=2048, soft-capped.
// ---------------------------------------------------------------------------
__global__ __launch_bounds__(256) void proj_if_kernel(
    const float* __restrict__ x, const float* __restrict__ Wi, const float* __restrict__ bi,
    const float* __restrict__ Wf, const float* __restrict__ bfg,
    float* __restrict__ ip, float* __restrict__ fp)
{
  const int tok = blockIdx.x;
  const int tid = threadIdx.x;
  const float* xr = x + (long)tok * EMB;
  float ai[8] = {}, af[8] = {};
  #pragma unroll
  for (int j = 0; j < 8; ++j) {
    const int e = tid + j * 256;
    const float xe = xr[e];
    const float4* wi4 = (const float4*)(Wi + (long)e * 8);
    const float4* wf4 = (const float4*)(Wf + (long)e * 8);
    const float4 a0 = wi4[0], a1 = wi4[1], b0 = wf4[0], b1 = wf4[1];
    ai[0] += xe * a0.x; ai[1] += xe * a0.y; ai[2] += xe * a0.z; ai[3] += xe * a0.w;
    ai[4] += xe * a1.x; ai[5] += xe * a1.y; ai[6] += xe * a1.z; ai[7] += xe * a1.w;
    af[0] += xe * b0.x; af[1] += xe * b0.y; af[2] += xe * b0.z; af[3] += xe * b0.w;
    af[4] += xe * b1.x; af[5] += xe * b1.y; af[6] += xe * b1.z; af[7] += xe * b1.w;
  }
  #pragma unroll
  for (int hh = 0; hh < 8; ++hh)
    for (int off = 32; off; off >>= 1) {
      ai[hh] += __shfl_xor(ai[hh], off);
      af[hh] += __shfl_xor(af[hh], off);
    }
  __shared__ float red[4][16];
  const int lane = tid & 63, wid = tid >> 6;
  if (lane == 0) {
    #pragma unroll
    for (int hh = 0; hh < 8; ++hh) { red[wid][hh] = ai[hh]; red[wid][hh + 8] = af[hh]; }
  }
  __syncthreads();
  if (tid < 16) {
    const float v = red[0][tid] + red[1][tid] + red[2][tid] + red[3][tid];
    const int b = tok >> 10, s = tok & 1023;
    if (tid < 8) {
      const float zv = v + bi[tid];
      ip[(long)(b * NH_ + tid) * S_LEN + s] = 15.0f * tanhf(zv * (1.0f / 15.0f));
    } else {
      const int hh = tid - 8;
      const float zv = v + bfg[hh];
      fp[(long)(b * NH_ + hh) * S_LEN + s] = 15.0f * tanhf(zv * (1.0f / 15.0f));
    }
  }
}

// ---------------------------------------------------------------------------
// Per (b,h): logsigmoid, cumsum cf, a = i_pre - cf, running max m, vecM = cf+m.
// ---------------------------------------------------------------------------
__global__ __launch_bounds__(1024) void gates_kernel(
    const float* __restrict__ fp, const float* __restrict__ ip,
    float* __restrict__ aArr, float* __restrict__ mArr, float* __restrict__ vMArr)
{
  const int bh = blockIdx.x;
  const int s = threadIdx.x;
  __shared__ float sh[1024];
  const float f = fp[(long)bh * S_LEN + s];
  const float lsg = fminf(f, 0.0f) - log1pf(expf(-fabsf(f)));  // log_sigmoid
  float v = lsg;
  sh[s] = v; __syncthreads();
  for (int off = 1; off < 1024; off <<= 1) {
    const float o = (s >= off) ? sh[s - off] : 0.0f;
    __syncthreads();
    v += o; sh[s] = v;
    __syncthreads();
  }
  const float cf = v;
  const float a = ip[(long)bh * S_LEN + s] - cf;
  v = a;
  sh[s] = v; __syncthreads();
  for (int off = 1; off < 1024; off <<= 1) {
    const float o = (s >= off) ? sh[s - off] : -3.0e38f;
    __syncthreads();
    v = fmaxf(v, o); sh[s] = v;
    __syncthreads();
  }
  aArr[(long)bh * S_LEN + s] = a;
  mArr[(long)bh * S_LEN + s] = v;
  vMArr[(long)bh * S_LEN + s] = cf + v;
}

// ---------------------------------------------------------------------------
// Fused mLSTM attention, triangle-paired for causal load balance (R7 version).
// ---------------------------------------------------------------------------
__global__ __launch_bounds__(256) void att_fused_kernel(
    const _Float16* __restrict__ qkvo, const _Float16* __restrict__ vt,
    const float* __restrict__ aArr, const float* __restrict__ mArr,
    const float* __restrict__ vMArr, _Float16* __restrict__ hb)
{
  __shared__ _Float16 Qs[2][32 * 256];   // swizzled: 32 chunks/row, ^(row&7)
  __shared__ _Float16 Ws[2][32 * 128];   // swizzled: 16 chunks/row, ^((row&7)<<1)
  __shared__ float nsh[2][4][32];
  __shared__ float invs[2][32];
  const int tid = threadIdx.x;
  const int lane = tid & 63, wid = tid >> 6;
  const int bh = blockIdx.y;
  const int b = bh >> 3, h = bh & 7;
  const int r0[2] = { (int)blockIdx.x * 32, (31 - (int)blockIdx.x) * 32 };
  const _Float16* Qg = qkvo + (long)(b * S_LEN) * NQKVO + h * DH_;
  const _Float16* Kg = qkvo + (long)(b * S_LEN) * NQKVO + 2048;
  const _Float16* Vt = vt + (long)b * DH_ * S_LEN;
  const float* aA = aArr + (long)bh * S_LEN;
  const float* mA = mArr + (long)bh * S_LEN;
  const int lrow = lane & 15, kseg = lane >> 4;
  const int tbase = 32 * wid;

  #pragma unroll
  for (int i = 0; i < 8; ++i) {
    const int cbase = (i * 4 + wid) * 64;
    const int c = cbase + lane;
    const int sub = c >> 10, row = (c >> 5) & 31, slot = c & 31;
    gload16(Qg + (long)(r0[sub] + row) * NQKVO + (slot ^ (row & 7)) * 8,
            (char*)Qs + cbase * 16);
  }

  float m_s[2][2][4];
  #pragma unroll
  for (int sub = 0; sub < 2; ++sub)
    #pragma unroll
    for (int m = 0; m < 2; ++m)
      #pragma unroll
      for (int i = 0; i < 4; ++i)
        m_s[sub][m][i] = mA[r0[sub] + m * 16 + kseg * 4 + i];
  __syncthreads();   // Q staged (drains vmcnt)

  f32x4 hacc[2][2][4] = {};
  float nacc[2][2][4] = {};
  for (int n0 = 0; n0 <= r0[1]; n0 += 128) {
    f32x4 acc[2][2][2] = {};
    for (int k0 = 0; k0 < DH_; k0 += 32) {
      f16x8 fb[2];
      #pragma unroll
      for (int n = 0; n < 2; ++n)
        fb[n] = *(const f16x8*)(Kg + (long)(n0 + tbase + n * 16 + lrow) * NQKVO + k0 + kseg * 8);
      const int chunk = (k0 >> 3) + kseg;
      __builtin_amdgcn_s_setprio(1);
      #pragma unroll
      for (int sub = 0; sub < 2; ++sub) {
        if (n0 > r0[sub]) continue;
        #pragma unroll
        for (int m = 0; m < 2; ++m) {
          const int qrow = m * 16 + lrow;
          const f16x8 fa = *(const f16x8*)&Qs[sub][qrow * 256 + ((chunk ^ (qrow & 7)) << 3)];
          #pragma unroll
          for (int n = 0; n < 2; ++n)
            acc[sub][m][n] = __builtin_amdgcn_mfma_f32_16x16x32_f16(fa, fb[n], acc[sub][m][n], 0, 0, 0);
        }
      }
      __builtin_amdgcn_s_setprio(0);
    }
    float a_t[2];
    #pragma unroll
    for (int n = 0; n < 2; ++n) a_t[n] = aA[n0 + tbase + n * 16 + lrow];
    #pragma unroll
    for (int sub = 0; sub < 2; ++sub) {
      if (n0 > r0[sub]) continue;
      #pragma unroll
      for (int m = 0; m < 2; ++m)
        #pragma unroll
        for (int n = 0; n < 2; ++n)
          #pragma unroll
          for (int i = 0; i < 4; ++i) {
            const int sr = m * 16 + kseg * 4 + i;
            const int t  = tbase + n * 16 + lrow;
            float w = 0.0f;
            if (n0 + t <= r0[sub] + sr)
              w = acc[sub][m][n][i] * 0.0625f * expf(a_t[n] - m_s[sub][m][i]);
            nacc[sub][m][i] += w;
            Ws[sub][sr * 128 + (((t >> 3) ^ ((sr & 7) << 1)) << 3) + (t & 7)] = f2h(w);
          }
    }
    __syncthreads();
    for (int kt = 0; kt < 128; kt += 32) {
      f16x8 vb[4];
      #pragma unroll
      for (int n = 0; n < 4; ++n)
        vb[n] = *(const f16x8*)(Vt + (long)(64 * wid + n * 16 + lrow) * S_LEN + n0 + kt + kseg * 8);
      const int chunk = (kt >> 3) + kseg;
      __builtin_amdgcn_s_setprio(1);
      #pragma unroll
      for (int sub = 0; sub < 2; ++sub) {
        if (n0 > r0[sub]) continue;
        #pragma unroll
        for (int m = 0; m < 2; ++m) {
          const int row = m * 16 + lrow;
          const f16x8 wa = *(const f16x8*)&Ws[sub][row * 128 + ((chunk ^ ((row & 7) << 1)) << 3)];
          #pragma unroll
          for (int n = 0; n < 4; ++n)
            hacc[sub][m][n] = __builtin_amdgcn_mfma_f32_16x16x32_f16(wa, vb[n], hacc[sub][m][n], 0, 0, 0);
        }
      }
      __builtin_amdgcn_s_setprio(0);
    }
    __syncthreads();
  }
  #pragma unroll
  for (int sub = 0; sub < 2; ++sub)
    #pragma unroll
    for (int m = 0; m < 2; ++m)
      #pragma unroll
      for (int i = 0; i < 4; ++i) {
        float v = nacc[sub][m][i];
        v += __shfl_xor(v, 1); v += __shfl_xor(v, 2);
        v += __shfl_xor(v, 4); v += __shfl_xor(v, 8);
        if (lrow == 0) nsh[sub][wid][m * 16 + kseg * 4 + i] = v;
      }
  __syncthreads();
  if (tid < 64) {
    const int sub = tid >> 5, sr = tid & 31;
    const float tot = nsh[sub][0][sr] + nsh[sub][1][sr] + nsh[sub][2][sr] + nsh[sub][3][sr];
    const float vm = vMArr[(long)bh * S_LEN + r0[sub] + sr];
    const float vecN = fmaxf(fabsf(tot), expf(-vm));
    invs[sub][sr] = 1.0f / (vecN + 1e-6f);
  }
  __syncthreads();
  #pragma unroll
  for (int sub = 0; sub < 2; ++sub)
    #pragma unroll
    for (int m = 0; m < 2; ++m)
      #pragma unroll
      for (int n = 0; n < 4; ++n)
        #pragma unroll
        for (int i = 0; i < 4; ++i) {
          const int row = m * 16 + kseg * 4 + i;
          const int d = 64 * wid + n * 16 + lrow;
          hb[((long)bh * S_LEN + r0[sub] + row) * DH_ + d] = f2h(hacc[sub][m][n][i] * invs[sub][row]);
        }
}

// ---------------------------------------------------------------------------
// One wave per (token, head) row: LN over DH=256 (f32), *gamma, *sigmoid(o).
// ---------------------------------------------------------------------------
__global__ __launch_bounds__(256) void ln_gate_kernel(
    const _Float16* __restrict__ hbuf,
    const _Float16* __restrict__ qkvo, const float* __restrict__ gamma,
    _Float16* __restrict__ u)
{
  const int wid = threadIdx.x >> 6, lane = threadIdx.x & 63;
  const int row = blockIdx.x * 4 + wid;   // row = tok*8 + h
  const int tok = row >> 3, h = row & 7;
  const int b = tok >> 10, s = tok & 1023;
  const int bh = b * NH_ + h;
  const f16x4 hv = *(const f16x4*)(hbuf + ((long)bh * S_LEN + s) * DH_ + lane * 4);
  const float v0 = (float)hv[0], v1 = (float)hv[1], v2 = (float)hv[2], v3 = (float)hv[3];
  float s1 = v0 + v1 + v2 + v3;
  float s2 = v0 * v0 + v1 * v1 + v2 * v2 + v3 * v3;
  for (int off = 32; off; off >>= 1) { s1 += __shfl_xor(s1, off); s2 += __shfl_xor(s2, off); }
  const float mu = s1 * (1.0f / 256.0f);
  const float var = s2 * (1.0f / 256.0f) - mu * mu;
  const float rs = rsqrtf(var + 1e-6f);
  const float4 g = *(const float4*)(gamma + h * DH_ + lane * 4);
  const f16x4 ov = *(const f16x4*)(qkvo + (long)tok * NQKVO + 2560 + h * DH_ + lane * 4);
  f16x4 res;
  res[0] = f2h((v0 - mu) * rs * g.x * (1.0f / (1.0f + expf(-(float)ov[0]))));
  res[1] = f2h((v1 - mu) * rs * g.y * (1.0f / (1.0f + expf(-(float)ov[1]))));
  res[2] = f2h((v2 - mu) * rs * g.z * (1.0f / (1.0f + expf(-(float)ov[2]))));
  res[3] = f2h((v3 - mu) * rs * g.w * (1.0f / (1.0f + expf(-(float)ov[3]))));
  *(f16x4*)(u + (long)tok * EMB + h * DH_ + lane * 4) = res;
}

// ---------------------------------------------------------------------------
extern "C" void kernel_launch(void* const* d_in, const int* in_sizes, int n_in,
                              void* d_out, int out_size, void* d_ws, size_t ws_size,
                              hipStream_t stream)
{
  (void)in_sizes; (void)n_in; (void)out_size; (void)ws_size;
  const float* x     = (const float*)d_in[0];
  const float* Wq    = (const float*)d_in[1];
  const float* Wk    = (const float*)d_in[2];
  const float* Wv    = (const float*)d_in[3];
  const float* Wog   = (const float*)d_in[4];
  const float* Wi    = (const float*)d_in[5];
  const float* bi    = (const float*)d_in[6];
  const float* Wf    = (const float*)d_in[7];
  const float* bfg   = (const float*)d_in[8];
  const float* gamma = (const float*)d_in[9];
  const float* Wout  = (const float*)d_in[10];

  char* base = (char*)d_ws;
  size_t off = 0;
  auto take = [&](size_t bytes) -> char* {
    char* p = base + off;
    off += (bytes + 255) & ~(size_t)255;
    return p;
  };
  _Float16* xh    = (_Float16*)take((size_t)TOKENS * EMB * 2);        //  8 MB
  _Float16* WcatT = (_Float16*)take((size_t)NQKVO * EMB * 2);         // 19 MB
  _Float16* WoutT = (_Float16*)take((size_t)EMB * EMB * 2);           //  8 MB
  _Float16* qkvo  = (_Float16*)take((size_t)TOKENS * NQKVO * 2);      // 19 MB
  _Float16* vt    = (_Float16*)take((size_t)2 * DH_ * S_LEN * 2);     //  1 MB
  _Float16* hb    = (_Float16*)take((size_t)NBH * S_LEN * DH_ * 2);   //  8 MB
  float*    ip    = (float*)take((size_t)NBH * S_LEN * 4);
  float*    fp    = (float*)take((size_t)NBH * S_LEN * 4);
  float*    aA    = (float*)take((size_t)NBH * S_LEN * 4);
  float*    mA    = (float*)take((size_t)NBH * S_LEN * 4);
  float*    vM    = (float*)take((size_t)NBH * S_LEN * 4);
  _Float16* ub    = xh;   // xh dead after QKVO GEMM
  float*    y     = (float*)d_out;

  const dim3 blk(256);
  // --- prep: x cast + all weight transposes (2 launches) ---
  cast_f16_kernel<<<dim3((TOKENS * EMB) / (256 * 8)), blk, 0, stream>>>(x, xh, (long)TOKENS * EMB);
  transpose_all_kernel<<<dim3(3328), blk, 0, stream>>>(Wq, Wk, Wv, Wog, Wout, WcatT, WoutT);
  // --- fused QKVO projection: [2048,4608] = xh @ WcatT^T (16 m x 18 n, 128x256 tiles) ---
  gemm_wide_kernel<_Float16><<<dim3(16 * 18), blk, 0, stream>>>(
      xh, WcatT, qkvo, EMB, EMB, EMB, NQKVO, 16);
  // --- V^T per batch ---
  transpose_cast_kernel<_Float16><<<dim3(4, 16, 2), blk, 0, stream>>>(
      qkvo + 2304, NQKVO, vt, S_LEN, (long)S_LEN * NQKVO, (long)DH_ * S_LEN);
  // --- gates ---
  proj_if_kernel<<<dim3(TOKENS), blk, 0, stream>>>(x, Wi, bi, Wf, bfg, ip, fp);
  gates_kernel<<<dim3(NBH), dim3(1024), 0, stream>>>(fp, ip, aA, mA, vM);
  // --- fused mLSTM backend ---
  att_fused_kernel<<<dim3(16, NBH), blk, 0, stream>>>(qkvo, vt, aA, mA, vM, hb);
  // --- layernorm + output gate ---
  ln_gate_kernel<<<dim3(TOKENS * NH_ / 4), blk, 0, stream>>>(hb, qkvo, gamma, ub);
  // --- output projection (16 m x 16 n, 128x128 tiles, R6 config) ---
  gemm_bt_kernel<float, 128><<<dim3(16 * 16), blk, 0, stream>>>(
      ub, WoutT, y, EMB, EMB, EMB, EMB, 0L, 0L, 0L, 1, 16, 0);
}

// Round 9
// 212.324 us; speedup vs baseline: 1.3155x; 1.0202x over previous
//
#include <hip/hip_runtime.h>
#include <math.h>

#define S_LEN  1024
#define EMB    2048
#define NH_    8
#define DH_    256
#define TOKENS 2048   // B*S
#define NBH    16     // B*NH
#define NQKVO  4608   // 2048 q | 256 k | 256 v | 2048 o

typedef __attribute__((ext_vector_type(4))) float    f32x4;
typedef __attribute__((ext_vector_type(8))) _Float16 f16x8;
typedef __attribute__((ext_vector_type(4))) _Float16 f16x4;

__device__ __forceinline__ _Float16 f2h(float f) { return (_Float16)f; }

// async global->LDS, 16B per lane; LDS dest = wave-uniform base + lane*16
__device__ __forceinline__ void gload16(const void* g, void* l) {
  __builtin_amdgcn_global_load_lds(
      (const __attribute__((address_space(1))) void*)g,
      (__attribute__((address_space(3))) void*)l, 16, 0, 0);
}

// ---------------------------------------------------------------------------
// Fused weight transposes (Wq,Wk,Wv,Wog -> WcatT; Wout -> WoutT), one launch.
// ---------------------------------------------------------------------------
__global__ __launch_bounds__(256) void transpose_all_kernel(
    const float* __restrict__ Wq, const float* __restrict__ Wk,
    const float* __restrict__ Wv, const float* __restrict__ Wog,
    const float* __restrict__ Wout,
    _Float16* __restrict__ WcatT, _Float16* __restrict__ WoutT)
{
  int t = blockIdx.x;
  const float* in; _Float16* out; int ldi, ct;
  if (t < 1024)      { in = Wq;   out = WcatT;                    ldi = 2048; ct = 32; }
  else if (t < 1152) { t -= 1024; in = Wk;  out = WcatT + (long)2048 * EMB; ldi = 256; ct = 4; }
  else if (t < 1280) { t -= 1152; in = Wv;  out = WcatT + (long)2304 * EMB; ldi = 256; ct = 4; }
  else if (t < 2304) { t -= 1280; in = Wog; out = WcatT + (long)2560 * EMB; ldi = 2048; ct = 32; }
  else               { t -= 2304; in = Wout; out = WoutT;         ldi = 2048; ct = 32; }
  const long c0 = (long)(t % ct) * 64, r0 = (long)(t / ct) * 64;
  __shared__ float tl[64][65];
  const int lx = threadIdx.x & 63, ly = threadIdx.x >> 6;
  #pragma unroll
  for (int i = 0; i < 16; ++i)
    tl[ly + i * 4][lx] = in[(r0 + ly + i * 4) * ldi + c0 + lx];
  __syncthreads();
  #pragma unroll
  for (int i = 0; i < 16; ++i)
    out[(c0 + ly + i * 4) * EMB + r0 + lx] = f2h(tl[lx][ly + i * 4]);
}

// ---------------------------------------------------------------------------
// Tiled transpose + cast to f16 (f16 input path used for V^T).
// ---------------------------------------------------------------------------
template<typename TIN>
__global__ __launch_bounds__(256) void transpose_cast_kernel(
    const TIN* __restrict__ in, long ldi, _Float16* __restrict__ out, long ldo,
    long sIn, long sOut)
{
  __shared__ float t[64][65];
  const int lx = threadIdx.x & 63, ly = threadIdx.x >> 6;
  const long r0 = (long)blockIdx.y * 64, c0 = (long)blockIdx.x * 64;
  const TIN* ip = in + (long)blockIdx.z * sIn;
  _Float16* op = out + (long)blockIdx.z * sOut;
  #pragma unroll
  for (int i = 0; i < 16; ++i)
    t[ly + i * 4][lx] = (float)ip[(r0 + ly + i * 4) * ldi + c0 + lx];
  __syncthreads();
  #pragma unroll
  for (int i = 0; i < 16; ++i)
    op[(c0 + ly + i * 4) * ldo + r0 + lx] = f2h(t[lx][ly + i * 4]);
}

// ---------------------------------------------------------------------------
// f16 GEMM, 128x128 tile, BK=32, 4 waves (2x2), 3-deep prefetch, counted
// vmcnt; XOR-swizzled LDS (verified conflict-free R6); bijective XCD swizzle.
// The R6 known-good config: 576-block grids run 2.25 blocks/CU.
// ---------------------------------------------------------------------------
template<typename CT, int BM>
__global__ __launch_bounds__(256) void gemm_bt_kernel(
    const _Float16* __restrict__ Ag, const _Float16* __restrict__ Btg,
    CT* __restrict__ Cg, int K, int lda, int ldb, int ldc,
    long sA, long sB, long sC, int zdivB, int mtiles, int causal)
{
  constexpr int MR = BM / 32;
  __shared__ _Float16 As[3][BM * 32];
  __shared__ _Float16 Bs[3][128 * 32];
  const int tid = threadIdx.x;
  const int lane = tid & 63, wid = tid >> 6;
  const int cpx = gridDim.x >> 3;
  const int wg = ((int)blockIdx.x & 7) * cpx + ((int)blockIdx.x >> 3);
  const int m0 = (wg % mtiles) * BM;
  const int n0 = (wg / mtiles) * 128;
  const int z  = blockIdx.z;
  const _Float16* Ap = Ag + (long)z * sA + (long)m0 * lda;
  const _Float16* Bp = Btg + (long)(z / zdivB) * sB + (long)n0 * ldb;
  const int wr = wid >> 1, wc = wid & 1;
  const int lrow = lane & 15, kseg = lane >> 4;
  const int kl = causal ? ((m0 + BM < K) ? m0 + BM : K) : K;

  auto stage = [&](int b, int k0) {
    #pragma unroll
    for (int i = 0; i < BM / 64; ++i) {
      const int cbase = (i * 4 + wid) * 64;
      const int row = (cbase >> 2) + (lane >> 2);
      const int src = ((lane & 3) ^ ((row >> 1) & 3)) * 8;
      gload16(Ap + (long)row * lda + k0 + src, (char*)As[b] + cbase * 16);
    }
    #pragma unroll
    for (int i = 0; i < 2; ++i) {
      const int cbase = (i * 4 + wid) * 64;
      const int row = (cbase >> 2) + (lane >> 2);
      const int src = ((lane & 3) ^ ((row >> 1) & 3)) * 8;
      gload16(Bp + (long)row * ldb + k0 + src, (char*)Bs[b] + cbase * 16);
    }
  };

  const int nt = kl >> 5;
  f32x4 acc[MR][4] = {};
  stage(0, 0);
  if (nt > 1) stage(1, 32);
  for (int t = 0; t < nt; ++t) {
    if (t + 2 < nt) {
      stage((t + 2) % 3, (t + 2) * 32);
      asm volatile("s_waitcnt vmcnt(8)" ::: "memory");
    } else if (t + 1 < nt) {
      asm volatile("s_waitcnt vmcnt(4)" ::: "memory");
    } else {
      asm volatile("s_waitcnt vmcnt(0)" ::: "memory");
    }
    __builtin_amdgcn_s_barrier();
    __builtin_amdgcn_sched_barrier(0);
    const int buf = t % 3;
    f16x8 fa[MR], fb[4];
    #pragma unroll
    for (int m = 0; m < MR; ++m) {
      const int row = wr * (BM / 2) + m * 16 + lrow;
      fa[m] = *(const f16x8*)&As[buf][row * 32 + ((kseg ^ ((row >> 1) & 3)) << 3)];
    }
    #pragma unroll
    for (int n = 0; n < 4; ++n) {
      const int row = wc * 64 + n * 16 + lrow;
      fb[n] = *(const f16x8*)&Bs[buf][row * 32 + ((kseg ^ ((row >> 1) & 3)) << 3)];
    }
    #pragma unroll
    for (int m = 0; m < MR; ++m)
      #pragma unroll
      for (int n = 0; n < 4; ++n)
        acc[m][n] = __builtin_amdgcn_mfma_f32_16x16x32_f16(fa[m], fb[n], acc[m][n], 0, 0, 0);
    __builtin_amdgcn_s_barrier();
  }
  CT* Cp = Cg + (long)z * sC;
  #pragma unroll
  for (int m = 0; m < MR; ++m)
    #pragma unroll
    for (int n = 0; n < 4; ++n)
      #pragma unroll
      for (int i = 0; i < 4; ++i) {
        const int r = m0 + wr * (BM / 2) + m * 16 + kseg * 4 + i;  // row=(lane>>4)*4+i (m89)
        const int c = n0 + wc * 64 + n * 16 + lrow;                // col=lane&15
        Cp[(long)r * ldc + c] = (CT)acc[m][n][i];
      }
}

// ---------------------------------------------------------------------------
// Fused: x -> xh (f16 cast) + i/f gate projections (per-token dot products).
// Both need the full x row; one global read pass instead of two.
// ---------------------------------------------------------------------------
__global__ __launch_bounds__(256) void proj_if_cast_kernel(
    const float* __restrict__ x, const float* __restrict__ Wi, const float* __restrict__ bi,
    const float* __restrict__ Wf, const float* __restrict__ bfg,
    _Float16* __restrict__ xh, float* __restrict__ ip, float* __restrict__ fp)
{
  const int tok = blockIdx.x;
  const int tid = threadIdx.x;
  const float* xr = x + (long)tok * EMB;
  float ai[8] = {}, af[8] = {};
  #pragma unroll
  for (int j = 0; j < 8; ++j) {
    const int e = tid + j * 256;
    const float xe = xr[e];
    xh[(long)tok * EMB + e] = f2h(xe);
    const float4* wi4 = (const float4*)(Wi + (long)e * 8);
    const float4* wf4 = (const float4*)(Wf + (long)e * 8);
    const float4 a0 = wi4[0], a1 = wi4[1], b0 = wf4[0], b1 = wf4[1];
    ai[0] += xe * a0.x; ai[1] += xe * a0.y; ai[2] += xe * a0.z; ai[3] += xe * a0.w;
    ai[4] += xe * a1.x; ai[5] += xe * a1.y; ai[6] += xe * a1.z; ai[7] += xe * a1.w;
    af[0] += xe * b0.x; af[1] += xe * b0.y; af[2] += xe * b0.z; af[3] += xe * b0.w;
    af[4] += xe * b1.x; af[5] += xe * b1.y; af[6] += xe * b1.z; af[7] += xe * b1.w;
  }
  #pragma unroll
  for (int hh = 0; hh < 8; ++hh)
    for (int off = 32; off; off >>= 1) {
      ai[hh] += __shfl_xor(ai[hh], off);
      af[hh] += __shfl_xor(af[hh], off);
    }
  __shared__ float red[4][16];
  const int lane = tid & 63, wid = tid >> 6;
  if (lane == 0) {
    #pragma unroll
    for (int hh = 0; hh < 8; ++hh) { red[wid][hh] = ai[hh]; red[wid][hh + 8] = af[hh]; }
  }
  __syncthreads();
  if (tid < 16) {
    const float v = red[0][tid] + red[1][tid] + red[2][tid] + red[3][tid];
    const int b = tok >> 10, s = tok & 1023;
    if (tid < 8) {
      const float zv = v + bi[tid];
      ip[(long)(b * NH_ + tid) * S_LEN + s] = 15.0f * tanhf(zv * (1.0f / 15.0f));
    } else {
      const int hh = tid - 8;
      const float zv = v + bfg[hh];
      fp[(long)(b * NH_ + hh) * S_LEN + s] = 15.0f * tanhf(zv * (1.0f / 15.0f));
    }
  }
}

// ---------------------------------------------------------------------------
// Per (b,h): logsigmoid, cumsum cf, a = i_pre - cf, running max m, vecM = cf+m.
// ---------------------------------------------------------------------------
__global__ __launch_bounds__(1024) void gates_kernel(
    const float* __restrict__ fp, const float* __restrict__ ip,
    float* __restrict__ aArr, float* __restrict__ mArr, float* __restrict__ vMArr)
{
  const int bh = blockIdx.x;
  const int s = threadIdx.x;
  __shared__ float sh[1024];
  const float f = fp[(long)bh * S_LEN + s];
  const float lsg = fminf(f, 0.0f) - log1pf(expf(-fabsf(f)));  // log_sigmoid
  float v = lsg;
  sh[s] = v; __syncthreads();
  for (int off = 1; off < 1024; off <<= 1) {
    const float o = (s >= off) ? sh[s - off] : 0.0f;
    __syncthreads();
    v += o; sh[s] = v;
    __syncthreads();
  }
  const float cf = v;
  const float a = ip[(long)bh * S_LEN + s] - cf;
  v = a;
  sh[s] = v; __syncthreads();
  for (int off = 1; off < 1024; off <<= 1) {
    const float o = (s >= off) ? sh[s - off] : -3.0e38f;
    __syncthreads();
    v = fmaxf(v, o); sh[s] = v;
    __syncthreads();
  }
  aArr[(long)bh * S_LEN + s] = a;
  mArr[(long)bh * S_LEN + s] = v;
  vMArr[(long)bh * S_LEN + s] = cf + v;
}

// ---------------------------------------------------------------------------
// Fused mLSTM attention, triangle-paired, QBLK=16 (R9: 512 blocks = 2/CU for
// TLP; R8's 256-block version had 1 block/CU and stalls fully exposed).
// Block (i, bh) owns q-subtiles i and 63-i (16 rows each): balanced passes.
// ---------------------------------------------------------------------------
__global__ __launch_bounds__(256) void att_fused_kernel(
    const _Float16* __restrict__ qkvo, const _Float16* __restrict__ vt,
    const float* __restrict__ aArr, const float* __restrict__ mArr,
    const float* __restrict__ vMArr, _Float16* __restrict__ hb)
{
  __shared__ _Float16 Qs[2][16 * 256];   // swizzled: 32 chunks/row, ^(row&7)
  __shared__ _Float16 Ws[2][16 * 128];   // swizzled: 16 chunks/row, ^((row&7)<<1)
  __shared__ float nsh[2][4][16];
  __shared__ float invs[2][16];
  const int tid = threadIdx.x;
  const int lane = tid & 63, wid = tid >> 6;
  const int bh = blockIdx.y;
  const int b = bh >> 3, h = bh & 7;
  const int r0[2] = { (int)blockIdx.x * 16, (63 - (int)blockIdx.x) * 16 };
  const _Float16* Qg = qkvo + (long)(b * S_LEN) * NQKVO + h * DH_;
  const _Float16* Kg = qkvo + (long)(b * S_LEN) * NQKVO + 2048;
  const _Float16* Vt = vt + (long)b * DH_ * S_LEN;
  const float* aA = aArr + (long)bh * S_LEN;
  const float* mA = mArr + (long)bh * S_LEN;
  const int lrow = lane & 15, kseg = lane >> 4;
  const int tbase = 32 * wid;

  // stage Q both subtiles: 1024 chunks of 16B, 4 iters.
  // chunk c: sub=c>>9, row=(c>>5)&15, slot=c&31; src chunk = slot^(row&7).
  #pragma unroll
  for (int i = 0; i < 4; ++i) {
    const int cbase = (i * 4 + wid) * 64;
    const int c = cbase + lane;
    const int sub = c >> 9, row = (c >> 5) & 15, slot = c & 31;
    gload16(Qg + (long)(r0[sub] + row) * NQKVO + (slot ^ (row & 7)) * 8,
            (char*)Qs + cbase * 16);
  }

  float m_s[2][4];
  #pragma unroll
  for (int sub = 0; sub < 2; ++sub)
    #pragma unroll
    for (int i = 0; i < 4; ++i)
      m_s[sub][i] = mA[r0[sub] + kseg * 4 + i];
  __syncthreads();   // Q staged (drains vmcnt)

  f32x4 hacc[2][4] = {};
  float nacc[2][4] = {};
  for (int n0 = 0; n0 <= r0[1]; n0 += 128) {
    // ---- QK^T: K frags global->reg, shared across subtiles ----
    f32x4 acc[2][2] = {};
    for (int k0 = 0; k0 < DH_; k0 += 32) {
      f16x8 fb[2];
      #pragma unroll
      for (int n = 0; n < 2; ++n)
        fb[n] = *(const f16x8*)(Kg + (long)(n0 + tbase + n * 16 + lrow) * NQKVO + k0 + kseg * 8);
      const int chunk = (k0 >> 3) + kseg;
      __builtin_amdgcn_s_setprio(1);
      #pragma unroll
      for (int sub = 0; sub < 2; ++sub) {
        if (n0 > r0[sub]) continue;
        const f16x8 fa = *(const f16x8*)&Qs[sub][lrow * 256 + ((chunk ^ (lrow & 7)) << 3)];
        #pragma unroll
        for (int n = 0; n < 2; ++n)
          acc[sub][n] = __builtin_amdgcn_mfma_f32_16x16x32_f16(fa, fb[n], acc[sub][n], 0, 0, 0);
      }
      __builtin_amdgcn_s_setprio(0);
    }
    // ---- weighting -> Ws (swizzled), row-sum accumulation ----
    float a_t[2];
    #pragma unroll
    for (int n = 0; n < 2; ++n) a_t[n] = aA[n0 + tbase + n * 16 + lrow];
    #pragma unroll
    for (int sub = 0; sub < 2; ++sub) {
      if (n0 > r0[sub]) continue;
      #pragma unroll
      for (int n = 0; n < 2; ++n)
        #pragma unroll
        for (int i = 0; i < 4; ++i) {
          const int sr = kseg * 4 + i;              // local row 0..15
          const int t  = tbase + n * 16 + lrow;     // local col 0..127
          float w = 0.0f;
          if (n0 + t <= r0[sub] + sr)
            w = acc[sub][n][i] * 0.0625f * expf(a_t[n] - m_s[sub][i]);
          nacc[sub][i] += w;
          Ws[sub][sr * 128 + (((t >> 3) ^ ((sr & 7) << 1)) << 3) + (t & 7)] = f2h(w);
        }
    }
    __syncthreads();
    // ---- PV: V frags global->reg (shared), Ws from LDS ----
    for (int kt = 0; kt < 128; kt += 32) {
      f16x8 vb[4];
      #pragma unroll
      for (int n = 0; n < 4; ++n)
        vb[n] = *(const f16x8*)(Vt + (long)(64 * wid + n * 16 + lrow) * S_LEN + n0 + kt + kseg * 8);
      const int chunk = (kt >> 3) + kseg;
      __builtin_amdgcn_s_setprio(1);
      #pragma unroll
      for (int sub = 0; sub < 2; ++sub) {
        if (n0 > r0[sub]) continue;
        const f16x8 wa = *(const f16x8*)&Ws[sub][lrow * 128 + ((chunk ^ ((lrow & 7) << 1)) << 3)];
        #pragma unroll
        for (int n = 0; n < 4; ++n)
          hacc[sub][n] = __builtin_amdgcn_mfma_f32_16x16x32_f16(wa, vb[n], hacc[sub][n], 0, 0, 0);
      }
      __builtin_amdgcn_s_setprio(0);
    }
    __syncthreads();   // Ws reads done before next pass overwrites
  }
  // ---- row sums -> invn ----
  #pragma unroll
  for (int sub = 0; sub < 2; ++sub)
    #pragma unroll
    for (int i = 0; i < 4; ++i) {
      float v = nacc[sub][i];
      v += __shfl_xor(v, 1); v += __shfl_xor(v, 2);
      v += __shfl_xor(v, 4); v += __shfl_xor(v, 8);
      if (lrow == 0) nsh[sub][wid][kseg * 4 + i] = v;
    }
  __syncthreads();
  if (tid < 32) {
    const int sub = tid >> 4, sr = tid & 15;
    const float tot = nsh[sub][0][sr] + nsh[sub][1][sr] + nsh[sub][2][sr] + nsh[sub][3][sr];
    const float vm = vMArr[(long)bh * S_LEN + r0[sub] + sr];
    const float vecN = fmaxf(fabsf(tot), expf(-vm));
    invs[sub][sr] = 1.0f / (vecN + 1e-6f);
  }
  __syncthreads();
  #pragma unroll
  for (int sub = 0; sub < 2; ++sub)
    #pragma unroll
    for (int n = 0; n < 4; ++n)
      #pragma unroll
      for (int i = 0; i < 4; ++i) {
        const int row = kseg * 4 + i;
        const int d = 64 * wid + n * 16 + lrow;
        hb[((long)bh * S_LEN + r0[sub] + row) * DH_ + d] = f2h(hacc[sub][n][i] * invs[sub][row]);
      }
}

// ---------------------------------------------------------------------------
// One wave per (token, head) row: LN over DH=256 (f32), *gamma, *sigmoid(o).
// ---------------------------------------------------------------------------
__global__ __launch_bounds__(256) void ln_gate_kernel(
    const _Float16* __restrict__ hbuf,
    const _Float16* __restrict__ qkvo, const float* __restrict__ gamma,
    _Float16* __restrict__ u)
{
  const int wid = threadIdx.x >> 6, lane = threadIdx.x & 63;
  const int row = blockIdx.x * 4 + wid;   // row = tok*8 + h
  const int tok = row >> 3, h = row & 7;
  const int b = tok >> 10, s = tok & 1023;
  const int bh = b * NH_ + h;
  const f16x4 hv = *(const f16x4*)(hbuf + ((long)bh * S_LEN + s) * DH_ + lane * 4);
  const float v0 = (float)hv[0], v1 = (float)hv[1], v2 = (float)hv[2], v3 = (float)hv[3];
  float s1 = v0 + v1 + v2 + v3;
  float s2 = v0 * v0 + v1 * v1 + v2 * v2 + v3 * v3;
  for (int off = 32; off; off >>= 1) { s1 += __shfl_xor(s1, off); s2 += __shfl_xor(s2, off); }
  const float mu = s1 * (1.0f / 256.0f);
  const float var = s2 * (1.0f / 256.0f) - mu * mu;
  const float rs = rsqrtf(var + 1e-6f);
  const float4 g = *(const float4*)(gamma + h * DH_ + lane * 4);
  const f16x4 ov = *(const f16x4*)(qkvo + (long)tok * NQKVO + 2560 + h * DH_ + lane * 4);
  f16x4 res;
  res[0] = f2h((v0 - mu) * rs * g.x * (1.0f / (1.0f + expf(-(float)ov[0]))));
  res[1] = f2h((v1 - mu) * rs * g.y * (1.0f / (1.0f + expf(-(float)ov[1]))));
  res[2] = f2h((v2 - mu) * rs * g.z * (1.0f / (1.0f + expf(-(float)ov[2]))));
  res[3] = f2h((v3 - mu) * rs * g.w * (1.0f / (1.0f + expf(-(float)ov[3]))));
  *(f16x4*)(u + (long)tok * EMB + h * DH_ + lane * 4) = res;
}

// ---------------------------------------------------------------------------
extern "C" void kernel_launch(void* const* d_in, const int* in_sizes, int n_in,
                              void* d_out, int out_size, void* d_ws, size_t ws_size,
                              hipStream_t stream)
{
  (void)in_sizes; (void)n_in; (void)out_size; (void)ws_size;
  const float* x     = (const float*)d_in[0];
  const float* Wq    = (const float*)d_in[1];
  const float* Wk    = (const float*)d_in[2];
  const float* Wv    = (const float*)d_in[3];
  const float* Wog   = (const float*)d_in[4];
  const float* Wi    = (const float*)d_in[5];
  const float* bi    = (const float*)d_in[6];
  const float* Wf    = (const float*)d_in[7];
  const float* bfg   = (const float*)d_in[8];
  const float* gamma = (const float*)d_in[9];
  const float* Wout  = (const float*)d_in[10];

  char* base = (char*)d_ws;
  size_t off = 0;
  auto take = [&](size_t bytes) -> char* {
    char* p = base + off;
    off += (bytes + 255) & ~(size_t)255;
    return p;
  };
  _Float16* xh    = (_Float16*)take((size_t)TOKENS * EMB * 2);        //  8 MB
  _Float16* WcatT = (_Float16*)take((size_t)NQKVO * EMB * 2);         // 19 MB
  _Float16* WoutT = (_Float16*)take((size_t)EMB * EMB * 2);           //  8 MB
  _Float16* qkvo  = (_Float16*)take((size_t)TOKENS * NQKVO * 2);      // 19 MB
  _Float16* vt    = (_Float16*)take((size_t)2 * DH_ * S_LEN * 2);     //  1 MB
  _Float16* hb    = (_Float16*)take((size_t)NBH * S_LEN * DH_ * 2);   //  8 MB
  float*    ip    = (float*)take((size_t)NBH * S_LEN * 4);
  float*    fp    = (float*)take((size_t)NBH * S_LEN * 4);
  float*    aA    = (float*)take((size_t)NBH * S_LEN * 4);
  float*    mA    = (float*)take((size_t)NBH * S_LEN * 4);
  float*    vM    = (float*)take((size_t)NBH * S_LEN * 4);
  _Float16* ub    = xh;   // xh dead after QKVO GEMM
  float*    y     = (float*)d_out;

  const dim3 blk(256);
  // --- prep: fused x-cast + i/f projections; all weight transposes ---
  proj_if_cast_kernel<<<dim3(TOKENS), blk, 0, stream>>>(x, Wi, bi, Wf, bfg, xh, ip, fp);
  transpose_all_kernel<<<dim3(3328), blk, 0, stream>>>(Wq, Wk, Wv, Wog, Wout, WcatT, WoutT);
  // --- fused QKVO projection: [2048,4608] = xh @ WcatT^T (R6 config, 576 blocks) ---
  gemm_bt_kernel<_Float16, 128><<<dim3(36 * 16), blk, 0, stream>>>(
      xh, WcatT, qkvo, EMB, EMB, EMB, NQKVO, 0L, 0L, 0L, 1, 16, 0);
  // --- V^T per batch ---
  transpose_cast_kernel<_Float16><<<dim3(4, 16, 2), blk, 0, stream>>>(
      qkvo + 2304, NQKVO, vt, S_LEN, (long)S_LEN * NQKVO, (long)DH_ * S_LEN);
  // --- gates ---
  gates_kernel<<<dim3(NBH), dim3(1024), 0, stream>>>(fp, ip, aA, mA, vM);
  // --- fused mLSTM backend (QBLK=16 pairs, 512 blocks) ---
  att_fused_kernel<<<dim3(32, NBH), blk, 0, stream>>>(qkvo, vt, aA, mA, vM, hb);
  // --- layernorm + output gate ---
  ln_gate_kernel<<<dim3(TOKENS * NH_ / 4), blk, 0, stream>>>(hb, qkvo, gamma, ub);
  // --- output projection (16 m x 16 n, 128x128 tiles) ---
  gemm_bt_kernel<float, 128><<<dim3(16 * 16), blk, 0, stream>>>(
      ub, WoutT, y, EMB, EMB, EMB, EMB, 0L, 0L, 0L, 1, 16, 0);
}

// Round 10
// 191.504 us; speedup vs baseline: 1.4585x; 1.1087x over previous
//
#include <hip/hip_runtime.h>
#include <math.h>

#define S_LEN  1024
#define EMB    2048
#define NH_    8
#define DH_    256
#define TOKENS 2048   // B*S
#define NBH    16     // B*NH
#define NQKVO  4608   // 2048 q | 256 k | 256 v | 2048 o

typedef __attribute__((ext_vector_type(4))) float    f32x4;
typedef __attribute__((ext_vector_type(8))) _Float16 f16x8;
typedef __attribute__((ext_vector_type(4))) _Float16 f16x4;

__device__ __forceinline__ _Float16 f2h(float f) { return (_Float16)f; }

// async global->LDS, 16B per lane; LDS dest = wave-uniform base + lane*16
__device__ __forceinline__ void gload16(const void* g, void* l) {
  __builtin_amdgcn_global_load_lds(
      (const __attribute__((address_space(1))) void*)g,
      (__attribute__((address_space(3))) void*)l, 16, 0, 0);
}

// ---------------------------------------------------------------------------
// Fused weight transposes (Wq,Wk,Wv,Wog -> WcatT; Wout -> WoutT), one launch.
// ---------------------------------------------------------------------------
__global__ __launch_bounds__(256) void transpose_all_kernel(
    const float* __restrict__ Wq, const float* __restrict__ Wk,
    const float* __restrict__ Wv, const float* __restrict__ Wog,
    const float* __restrict__ Wout,
    _Float16* __restrict__ WcatT, _Float16* __restrict__ WoutT)
{
  int t = blockIdx.x;
  const float* in; _Float16* out; int ldi, ct;
  if (t < 1024)      { in = Wq;   out = WcatT;                    ldi = 2048; ct = 32; }
  else if (t < 1152) { t -= 1024; in = Wk;  out = WcatT + (long)2048 * EMB; ldi = 256; ct = 4; }
  else if (t < 1280) { t -= 1152; in = Wv;  out = WcatT + (long)2304 * EMB; ldi = 256; ct = 4; }
  else if (t < 2304) { t -= 1280; in = Wog; out = WcatT + (long)2560 * EMB; ldi = 2048; ct = 32; }
  else               { t -= 2304; in = Wout; out = WoutT;         ldi = 2048; ct = 32; }
  const long c0 = (long)(t % ct) * 64, r0 = (long)(t / ct) * 64;
  __shared__ float tl[64][65];
  const int lx = threadIdx.x & 63, ly = threadIdx.x >> 6;
  #pragma unroll
  for (int i = 0; i < 16; ++i)
    tl[ly + i * 4][lx] = in[(r0 + ly + i * 4) * ldi + c0 + lx];
  __syncthreads();
  #pragma unroll
  for (int i = 0; i < 16; ++i)
    out[(c0 + ly + i * 4) * EMB + r0 + lx] = f2h(tl[lx][ly + i * 4]);
}

// ---------------------------------------------------------------------------
// Tiled transpose + cast to f16 (f16 input path used for V^T).
// ---------------------------------------------------------------------------
template<typename TIN>
__global__ __launch_bounds__(256) void transpose_cast_kernel(
    const TIN* __restrict__ in, long ldi, _Float16* __restrict__ out, long ldo,
    long sIn, long sOut)
{
  __shared__ float t[64][65];
  const int lx = threadIdx.x & 63, ly = threadIdx.x >> 6;
  const long r0 = (long)blockIdx.y * 64, c0 = (long)blockIdx.x * 64;
  const TIN* ip = in + (long)blockIdx.z * sIn;
  _Float16* op = out + (long)blockIdx.z * sOut;
  #pragma unroll
  for (int i = 0; i < 16; ++i)
    t[ly + i * 4][lx] = (float)ip[(r0 + ly + i * 4) * ldi + c0 + lx];
  __syncthreads();
  #pragma unroll
  for (int i = 0; i < 16; ++i)
    op[(c0 + ly + i * 4) * ldo + r0 + lx] = f2h(t[lx][ly + i * 4]);
}

// ---------------------------------------------------------------------------
// f16 GEMM, 128x128 tile, BK=32, 4 waves (2x2), 3-deep prefetch, counted
// vmcnt; XOR-swizzled LDS (verified conflict-free R6); bijective XCD swizzle.
// ---------------------------------------------------------------------------
template<typename CT, int BM>
__global__ __launch_bounds__(256) void gemm_bt_kernel(
    const _Float16* __restrict__ Ag, const _Float16* __restrict__ Btg,
    CT* __restrict__ Cg, int K, int lda, int ldb, int ldc,
    long sA, long sB, long sC, int zdivB, int mtiles, int causal)
{
  constexpr int MR = BM / 32;
  __shared__ _Float16 As[3][BM * 32];
  __shared__ _Float16 Bs[3][128 * 32];
  const int tid = threadIdx.x;
  const int lane = tid & 63, wid = tid >> 6;
  const int cpx = gridDim.x >> 3;
  const int wg = ((int)blockIdx.x & 7) * cpx + ((int)blockIdx.x >> 3);
  const int m0 = (wg % mtiles) * BM;
  const int n0 = (wg / mtiles) * 128;
  const int z  = blockIdx.z;
  const _Float16* Ap = Ag + (long)z * sA + (long)m0 * lda;
  const _Float16* Bp = Btg + (long)(z / zdivB) * sB + (long)n0 * ldb;
  const int wr = wid >> 1, wc = wid & 1;
  const int lrow = lane & 15, kseg = lane >> 4;
  const int kl = causal ? ((m0 + BM < K) ? m0 + BM : K) : K;

  auto stage = [&](int b, int k0) {
    #pragma unroll
    for (int i = 0; i < BM / 64; ++i) {
      const int cbase = (i * 4 + wid) * 64;
      const int row = (cbase >> 2) + (lane >> 2);
      const int src = ((lane & 3) ^ ((row >> 1) & 3)) * 8;
      gload16(Ap + (long)row * lda + k0 + src, (char*)As[b] + cbase * 16);
    }
    #pragma unroll
    for (int i = 0; i < 2; ++i) {
      const int cbase = (i * 4 + wid) * 64;
      const int row = (cbase >> 2) + (lane >> 2);
      const int src = ((lane & 3) ^ ((row >> 1) & 3)) * 8;
      gload16(Bp + (long)row * ldb + k0 + src, (char*)Bs[b] + cbase * 16);
    }
  };

  const int nt = kl >> 5;
  f32x4 acc[MR][4] = {};
  stage(0, 0);
  if (nt > 1) stage(1, 32);
  for (int t = 0; t < nt; ++t) {
    if (t + 2 < nt) {
      stage((t + 2) % 3, (t + 2) * 32);
      asm volatile("s_waitcnt vmcnt(8)" ::: "memory");
    } else if (t + 1 < nt) {
      asm volatile("s_waitcnt vmcnt(4)" ::: "memory");
    } else {
      asm volatile("s_waitcnt vmcnt(0)" ::: "memory");
    }
    __builtin_amdgcn_s_barrier();
    __builtin_amdgcn_sched_barrier(0);
    const int buf = t % 3;
    f16x8 fa[MR], fb[4];
    #pragma unroll
    for (int m = 0; m < MR; ++m) {
      const int row = wr * (BM / 2) + m * 16 + lrow;
      fa[m] = *(const f16x8*)&As[buf][row * 32 + ((kseg ^ ((row >> 1) & 3)) << 3)];
    }
    #pragma unroll
    for (int n = 0; n < 4; ++n) {
      const int row = wc * 64 + n * 16 + lrow;
      fb[n] = *(const f16x8*)&Bs[buf][row * 32 + ((kseg ^ ((row >> 1) & 3)) << 3)];
    }
    #pragma unroll
    for (int m = 0; m < MR; ++m)
      #pragma unroll
      for (int n = 0; n < 4; ++n)
        acc[m][n] = __builtin_amdgcn_mfma_f32_16x16x32_f16(fa[m], fb[n], acc[m][n], 0, 0, 0);
    __builtin_amdgcn_s_barrier();
  }
  CT* Cp = Cg + (long)z * sC;
  #pragma unroll
  for (int m = 0; m < MR; ++m)
    #pragma unroll
    for (int n = 0; n < 4; ++n)
      #pragma unroll
      for (int i = 0; i < 4; ++i) {
        const int r = m0 + wr * (BM / 2) + m * 16 + kseg * 4 + i;  // row=(lane>>4)*4+i (m89)
        const int c = n0 + wc * 64 + n * 16 + lrow;                // col=lane&15
        Cp[(long)r * ldc + c] = (CT)acc[m][n][i];
      }
}

// ---------------------------------------------------------------------------
// Fused: x -> xh (f16 cast) + i/f gate projections.
// ---------------------------------------------------------------------------
__global__ __launch_bounds__(256) void proj_if_cast_kernel(
    const float* __restrict__ x, const float* __restrict__ Wi, const float* __restrict__ bi,
    const float* __restrict__ Wf, const float* __restrict__ bfg,
    _Float16* __restrict__ xh, float* __restrict__ ip, float* __restrict__ fp)
{
  const int tok = blockIdx.x;
  const int tid = threadIdx.x;
  const float* xr = x + (long)tok * EMB;
  float ai[8] = {}, af[8] = {};
  #pragma unroll
  for (int j = 0; j < 8; ++j) {
    const int e = tid + j * 256;
    const float xe = xr[e];
    xh[(long)tok * EMB + e] = f2h(xe);
    const float4* wi4 = (const float4*)(Wi + (long)e * 8);
    const float4* wf4 = (const float4*)(Wf + (long)e * 8);
    const float4 a0 = wi4[0], a1 = wi4[1], b0 = wf4[0], b1 = wf4[1];
    ai[0] += xe * a0.x; ai[1] += xe * a0.y; ai[2] += xe * a0.z; ai[3] += xe * a0.w;
    ai[4] += xe * a1.x; ai[5] += xe * a1.y; ai[6] += xe * a1.z; ai[7] += xe * a1.w;
    af[0] += xe * b0.x; af[1] += xe * b0.y; af[2] += xe * b0.z; af[3] += xe * b0.w;
    af[4] += xe * b1.x; af[5] += xe * b1.y; af[6] += xe * b1.z; af[7] += xe * b1.w;
  }
  #pragma unroll
  for (int hh = 0; hh < 8; ++hh)
    for (int off = 32; off; off >>= 1) {
      ai[hh] += __shfl_xor(ai[hh], off);
      af[hh] += __shfl_xor(af[hh], off);
    }
  __shared__ float red[4][16];
  const int lane = tid & 63, wid = tid >> 6;
  if (lane == 0) {
    #pragma unroll
    for (int hh = 0; hh < 8; ++hh) { red[wid][hh] = ai[hh]; red[wid][hh + 8] = af[hh]; }
  }
  __syncthreads();
  if (tid < 16) {
    const float v = red[0][tid] + red[1][tid] + red[2][tid] + red[3][tid];
    const int b = tok >> 10, s = tok & 1023;
    if (tid < 8) {
      const float zv = v + bi[tid];
      ip[(long)(b * NH_ + tid) * S_LEN + s] = 15.0f * tanhf(zv * (1.0f / 15.0f));
    } else {
      const int hh = tid - 8;
      const float zv = v + bfg[hh];
      fp[(long)(b * NH_ + hh) * S_LEN + s] = 15.0f * tanhf(zv * (1.0f / 15.0f));
    }
  }
}

// ---------------------------------------------------------------------------
// Per (b,h): logsigmoid, cumsum cf, a = i_pre - cf, running max m, vecM = cf+m.
// ---------------------------------------------------------------------------
__global__ __launch_bounds__(1024) void gates_kernel(
    const float* __restrict__ fp, const float* __restrict__ ip,
    float* __restrict__ aArr, float* __restrict__ mArr, float* __restrict__ vMArr)
{
  const int bh = blockIdx.x;
  const int s = threadIdx.x;
  __shared__ float sh[1024];
  const float f = fp[(long)bh * S_LEN + s];
  const float lsg = fminf(f, 0.0f) - log1pf(expf(-fabsf(f)));  // log_sigmoid
  float v = lsg;
  sh[s] = v; __syncthreads();
  for (int off = 1; off < 1024; off <<= 1) {
    const float o = (s >= off) ? sh[s - off] : 0.0f;
    __syncthreads();
    v += o; sh[s] = v;
    __syncthreads();
  }
  const float cf = v;
  const float a = ip[(long)bh * S_LEN + s] - cf;
  v = a;
  sh[s] = v; __syncthreads();
  for (int off = 1; off < 1024; off <<= 1) {
    const float o = (s >= off) ? sh[s - off] : -3.0e38f;
    __syncthreads();
    v = fmaxf(v, o); sh[s] = v;
    __syncthreads();
  }
  aArr[(long)bh * S_LEN + s] = a;
  mArr[(long)bh * S_LEN + s] = v;
  vMArr[(long)bh * S_LEN + s] = cf + v;
}

// ---------------------------------------------------------------------------
// Fused mLSTM attention, triangle-paired, QBLK=32 (R8 geometry — the R9
// QBLK=16 halving destroyed per-block K/V reuse).  R10: register-level
// prefetch pipelines for K frags (next k-step) and V frags (issue-early
// before the Ws barrier + next-kt during PV MFMAs) to hide global latency.
// ---------------------------------------------------------------------------
__global__ __launch_bounds__(256) void att_fused_kernel(
    const _Float16* __restrict__ qkvo, const _Float16* __restrict__ vt,
    const float* __restrict__ aArr, const float* __restrict__ mArr,
    const float* __restrict__ vMArr, _Float16* __restrict__ hb)
{
  __shared__ _Float16 Qs[2][32 * 256];   // swizzled: 32 chunks/row, ^(row&7)
  __shared__ _Float16 Ws[2][32 * 128];   // swizzled: 16 chunks/row, ^((row&7)<<1)
  __shared__ float nsh[2][4][32];
  __shared__ float invs[2][32];
  const int tid = threadIdx.x;
  const int lane = tid & 63, wid = tid >> 6;
  const int bh = blockIdx.y;
  const int b = bh >> 3, h = bh & 7;
  const int r0[2] = { (int)blockIdx.x * 32, (31 - (int)blockIdx.x) * 32 };
  const _Float16* Qg = qkvo + (long)(b * S_LEN) * NQKVO + h * DH_;
  const _Float16* Kg = qkvo + (long)(b * S_LEN) * NQKVO + 2048;
  const _Float16* Vt = vt + (long)b * DH_ * S_LEN;
  const float* aA = aArr + (long)bh * S_LEN;
  const float* mA = mArr + (long)bh * S_LEN;
  const int lrow = lane & 15, kseg = lane >> 4;
  const int tbase = 32 * wid;

  #pragma unroll
  for (int i = 0; i < 8; ++i) {
    const int cbase = (i * 4 + wid) * 64;
    const int c = cbase + lane;
    const int sub = c >> 10, row = (c >> 5) & 31, slot = c & 31;
    gload16(Qg + (long)(r0[sub] + row) * NQKVO + (slot ^ (row & 7)) * 8,
            (char*)Qs + cbase * 16);
  }

  float m_s[2][2][4];
  #pragma unroll
  for (int sub = 0; sub < 2; ++sub)
    #pragma unroll
    for (int m = 0; m < 2; ++m)
      #pragma unroll
      for (int i = 0; i < 4; ++i)
        m_s[sub][m][i] = mA[r0[sub] + m * 16 + kseg * 4 + i];
  __syncthreads();   // Q staged (drains vmcnt)

  f32x4 hacc[2][2][4] = {};
  float nacc[2][2][4] = {};
  for (int n0 = 0; n0 <= r0[1]; n0 += 128) {
    // ---- QK^T: K frags global->reg with next-step prefetch ----
    f32x4 acc[2][2][2] = {};
    f16x8 fb[2], fbn[2];
    #pragma unroll
    for (int n = 0; n < 2; ++n)
      fb[n] = *(const f16x8*)(Kg + (long)(n0 + tbase + n * 16 + lrow) * NQKVO + kseg * 8);
    #pragma unroll
    for (int k0 = 0; k0 < DH_; k0 += 32) {
      if (k0 + 32 < DH_) {
        #pragma unroll
        for (int n = 0; n < 2; ++n)
          fbn[n] = *(const f16x8*)(Kg + (long)(n0 + tbase + n * 16 + lrow) * NQKVO + k0 + 32 + kseg * 8);
      }
      const int chunk = (k0 >> 3) + kseg;
      __builtin_amdgcn_s_setprio(1);
      #pragma unroll
      for (int sub = 0; sub < 2; ++sub) {
        if (n0 > r0[sub]) continue;
        #pragma unroll
        for (int m = 0; m < 2; ++m) {
          const int qrow = m * 16 + lrow;
          const f16x8 fa = *(const f16x8*)&Qs[sub][qrow * 256 + ((chunk ^ (qrow & 7)) << 3)];
          #pragma unroll
          for (int n = 0; n < 2; ++n)
            acc[sub][m][n] = __builtin_amdgcn_mfma_f32_16x16x32_f16(fa, fb[n], acc[sub][m][n], 0, 0, 0);
        }
      }
      __builtin_amdgcn_s_setprio(0);
      fb[0] = fbn[0]; fb[1] = fbn[1];
    }
    // ---- weighting -> Ws (swizzled), row-sum accumulation ----
    float a_t[2];
    #pragma unroll
    for (int n = 0; n < 2; ++n) a_t[n] = aA[n0 + tbase + n * 16 + lrow];
    #pragma unroll
    for (int sub = 0; sub < 2; ++sub) {
      if (n0 > r0[sub]) continue;
      #pragma unroll
      for (int m = 0; m < 2; ++m)
        #pragma unroll
        for (int n = 0; n < 2; ++n)
          #pragma unroll
          for (int i = 0; i < 4; ++i) {
            const int sr = m * 16 + kseg * 4 + i;
            const int t  = tbase + n * 16 + lrow;
            float w = 0.0f;
            if (n0 + t <= r0[sub] + sr)
              w = acc[sub][m][n][i] * 0.0625f * expf(a_t[n] - m_s[sub][m][i]);
            nacc[sub][m][i] += w;
            Ws[sub][sr * 128 + (((t >> 3) ^ ((sr & 7) << 1)) << 3) + (t & 7)] = f2h(w);
          }
    }
    // ---- issue-early V loads for kt=0 (independent of the barrier) ----
    f16x8 vb[4], vbn[4];
    #pragma unroll
    for (int n = 0; n < 4; ++n)
      vb[n] = *(const f16x8*)(Vt + (long)(64 * wid + n * 16 + lrow) * S_LEN + n0 + kseg * 8);
    __syncthreads();
    // ---- PV: Ws from LDS, V frags pipelined ----
    #pragma unroll
    for (int kt = 0; kt < 128; kt += 32) {
      if (kt + 32 < 128) {
        #pragma unroll
        for (int n = 0; n < 4; ++n)
          vbn[n] = *(const f16x8*)(Vt + (long)(64 * wid + n * 16 + lrow) * S_LEN + n0 + kt + 32 + kseg * 8);
      }
      const int chunk = (kt >> 3) + kseg;
      __builtin_amdgcn_s_setprio(1);
      #pragma unroll
      for (int sub = 0; sub < 2; ++sub) {
        if (n0 > r0[sub]) continue;
        #pragma unroll
        for (int m = 0; m < 2; ++m) {
          const int row = m * 16 + lrow;
          const f16x8 wa = *(const f16x8*)&Ws[sub][row * 128 + ((chunk ^ ((row & 7) << 1)) << 3)];
          #pragma unroll
          for (int n = 0; n < 4; ++n)
            hacc[sub][m][n] = __builtin_amdgcn_mfma_f32_16x16x32_f16(wa, vb[n], hacc[sub][m][n], 0, 0, 0);
        }
      }
      __builtin_amdgcn_s_setprio(0);
      #pragma unroll
      for (int n = 0; n < 4; ++n) vb[n] = vbn[n];
    }
    __syncthreads();   // Ws reads done before next pass overwrites
  }
  // ---- row sums -> invn ----
  #pragma unroll
  for (int sub = 0; sub < 2; ++sub)
    #pragma unroll
    for (int m = 0; m < 2; ++m)
      #pragma unroll
      for (int i = 0; i < 4; ++i) {
        float v = nacc[sub][m][i];
        v += __shfl_xor(v, 1); v += __shfl_xor(v, 2);
        v += __shfl_xor(v, 4); v += __shfl_xor(v, 8);
        if (lrow == 0) nsh[sub][wid][m * 16 + kseg * 4 + i] = v;
      }
  __syncthreads();
  if (tid < 64) {
    const int sub = tid >> 5, sr = tid & 31;
    const float tot = nsh[sub][0][sr] + nsh[sub][1][sr] + nsh[sub][2][sr] + nsh[sub][3][sr];
    const float vm = vMArr[(long)bh * S_LEN + r0[sub] + sr];
    const float vecN = fmaxf(fabsf(tot), expf(-vm));
    invs[sub][sr] = 1.0f / (vecN + 1e-6f);
  }
  __syncthreads();
  #pragma unroll
  for (int sub = 0; sub < 2; ++sub)
    #pragma unroll
    for (int m = 0; m < 2; ++m)
      #pragma unroll
      for (int n = 0; n < 4; ++n)
        #pragma unroll
        for (int i = 0; i < 4; ++i) {
          const int row = m * 16 + kseg * 4 + i;
          const int d = 64 * wid + n * 16 + lrow;
          hb[((long)bh * S_LEN + r0[sub] + row) * DH_ + d] = f2h(hacc[sub][m][n][i] * invs[sub][row]);
        }
}

// ---------------------------------------------------------------------------
// One wave per (token, head) row: LN over DH=256 (f32), *gamma, *sigmoid(o).
// ---------------------------------------------------------------------------
__global__ __launch_bounds__(256) void ln_gate_kernel(
    const _Float16* __restrict__ hbuf,
    const _Float16* __restrict__ qkvo, const float* __restrict__ gamma,
    _Float16* __restrict__ u)
{
  const int wid = threadIdx.x >> 6, lane = threadIdx.x & 63;
  const int row = blockIdx.x * 4 + wid;   // row = tok*8 + h
  const int tok = row >> 3, h = row & 7;
  const int b = tok >> 10, s = tok & 1023;
  const int bh = b * NH_ + h;
  const f16x4 hv = *(const f16x4*)(hbuf + ((long)bh * S_LEN + s) * DH_ + lane * 4);
  const float v0 = (float)hv[0], v1 = (float)hv[1], v2 = (float)hv[2], v3 = (float)hv[3];
  float s1 = v0 + v1 + v2 + v3;
  float s2 = v0 * v0 + v1 * v1 + v2 * v2 + v3 * v3;
  for (int off = 32; off; off >>= 1) { s1 += __shfl_xor(s1, off); s2 += __shfl_xor(s2, off); }
  const float mu = s1 * (1.0f / 256.0f);
  const float var = s2 * (1.0f / 256.0f) - mu * mu;
  const float rs = rsqrtf(var + 1e-6f);
  const float4 g = *(const float4*)(gamma + h * DH_ + lane * 4);
  const f16x4 ov = *(const f16x4*)(qkvo + (long)tok * NQKVO + 2560 + h * DH_ + lane * 4);
  f16x4 res;
  res[0] = f2h((v0 - mu) * rs * g.x * (1.0f / (1.0f + expf(-(float)ov[0]))));
  res[1] = f2h((v1 - mu) * rs * g.y * (1.0f / (1.0f + expf(-(float)ov[1]))));
  res[2] = f2h((v2 - mu) * rs * g.z * (1.0f / (1.0f + expf(-(float)ov[2]))));
  res[3] = f2h((v3 - mu) * rs * g.w * (1.0f / (1.0f + expf(-(float)ov[3]))));
  *(f16x4*)(u + (long)tok * EMB + h * DH_ + lane * 4) = res;
}

// ---------------------------------------------------------------------------
extern "C" void kernel_launch(void* const* d_in, const int* in_sizes, int n_in,
                              void* d_out, int out_size, void* d_ws, size_t ws_size,
                              hipStream_t stream)
{
  (void)in_sizes; (void)n_in; (void)out_size; (void)ws_size;
  const float* x     = (const float*)d_in[0];
  const float* Wq    = (const float*)d_in[1];
  const float* Wk    = (const float*)d_in[2];
  const float* Wv    = (const float*)d_in[3];
  const float* Wog   = (const float*)d_in[4];
  const float* Wi    = (const float*)d_in[5];
  const float* bi    = (const float*)d_in[6];
  const float* Wf    = (const float*)d_in[7];
  const float* bfg   = (const float*)d_in[8];
  const float* gamma = (const float*)d_in[9];
  const float* Wout  = (const float*)d_in[10];

  char* base = (char*)d_ws;
  size_t off = 0;
  auto take = [&](size_t bytes) -> char* {
    char* p = base + off;
    off += (bytes + 255) & ~(size_t)255;
    return p;
  };
  _Float16* xh    = (_Float16*)take((size_t)TOKENS * EMB * 2);        //  8 MB
  _Float16* WcatT = (_Float16*)take((size_t)NQKVO * EMB * 2);         // 19 MB
  _Float16* WoutT = (_Float16*)take((size_t)EMB * EMB * 2);           //  8 MB
  _Float16* qkvo  = (_Float16*)take((size_t)TOKENS * NQKVO * 2);      // 19 MB
  _Float16* vt    = (_Float16*)take((size_t)2 * DH_ * S_LEN * 2);     //  1 MB
  _Float16* hb    = (_Float16*)take((size_t)NBH * S_LEN * DH_ * 2);   //  8 MB
  float*    ip    = (float*)take((size_t)NBH * S_LEN * 4);
  float*    fp    = (float*)take((size_t)NBH * S_LEN * 4);
  float*    aA    = (float*)take((size_t)NBH * S_LEN * 4);
  float*    mA    = (float*)take((size_t)NBH * S_LEN * 4);
  float*    vM    = (float*)take((size_t)NBH * S_LEN * 4);
  _Float16* ub    = xh;   // xh dead after QKVO GEMM
  float*    y     = (float*)d_out;

  const dim3 blk(256);
  // --- prep: fused x-cast + i/f projections; all weight transposes ---
  proj_if_cast_kernel<<<dim3(TOKENS), blk, 0, stream>>>(x, Wi, bi, Wf, bfg, xh, ip, fp);
  transpose_all_kernel<<<dim3(3328), blk, 0, stream>>>(Wq, Wk, Wv, Wog, Wout, WcatT, WoutT);
  // --- fused QKVO projection: [2048,4608] = xh @ WcatT^T (576 blocks) ---
  gemm_bt_kernel<_Float16, 128><<<dim3(36 * 16), blk, 0, stream>>>(
      xh, WcatT, qkvo, EMB, EMB, EMB, NQKVO, 0L, 0L, 0L, 1, 16, 0);
  // --- V^T per batch ---
  transpose_cast_kernel<_Float16><<<dim3(4, 16, 2), blk, 0, stream>>>(
      qkvo + 2304, NQKVO, vt, S_LEN, (long)S_LEN * NQKVO, (long)DH_ * S_LEN);
  // --- gates ---
  gates_kernel<<<dim3(NBH), dim3(1024), 0, stream>>>(fp, ip, aA, mA, vM);
  // --- fused mLSTM backend (QBLK=32 pairs, 256 blocks, reg-prefetch) ---
  att_fused_kernel<<<dim3(16, NBH), blk, 0, stream>>>(qkvo, vt, aA, mA, vM, hb);
  // --- layernorm + output gate ---
  ln_gate_kernel<<<dim3(TOKENS * NH_ / 4), blk, 0, stream>>>(hb, qkvo, gamma, ub);
  // --- output projection (16 m x 16 n, 128x128 tiles) ---
  gemm_bt_kernel<float, 128><<<dim3(16 * 16), blk, 0, stream>>>(
      ub, WoutT, y, EMB, EMB, EMB, EMB, 0L, 0L, 0L, 1, 16, 0);
}

// Round 11
// 187.314 us; speedup vs baseline: 1.4911x; 1.0224x over previous
//
#include <hip/hip_runtime.h>
#include <math.h>

#define S_LEN  1024
#define EMB    2048
#define NH_    8
#define DH_    256
#define TOKENS 2048   // B*S
#define NBH    16     // B*NH
#define NQKVO  4608   // 2048 q | 256 k | 256 v | 2048 o

typedef __attribute__((ext_vector_type(4))) float    f32x4;
typedef __attribute__((ext_vector_type(8))) _Float16 f16x8;
typedef __attribute__((ext_vector_type(4))) _Float16 f16x4;

__device__ __forceinline__ _Float16 f2h(float f) { return (_Float16)f; }

// async global->LDS, 16B per lane; LDS dest = wave-uniform base + lane*16
__device__ __forceinline__ void gload16(const void* g, void* l) {
  __builtin_amdgcn_global_load_lds(
      (const __attribute__((address_space(1))) void*)g,
      (__attribute__((address_space(3))) void*)l, 16, 0, 0);
}

// ---------------------------------------------------------------------------
// Fused weight transposes (Wq,Wk,Wv,Wog -> WcatT; Wout -> WoutT), one launch.
// ---------------------------------------------------------------------------
__global__ __launch_bounds__(256) void transpose_all_kernel(
    const float* __restrict__ Wq, const float* __restrict__ Wk,
    const float* __restrict__ Wv, const float* __restrict__ Wog,
    const float* __restrict__ Wout,
    _Float16* __restrict__ WcatT, _Float16* __restrict__ WoutT)
{
  int t = blockIdx.x;
  const float* in; _Float16* out; int ldi, ct;
  if (t < 1024)      { in = Wq;   out = WcatT;                    ldi = 2048; ct = 32; }
  else if (t < 1152) { t -= 1024; in = Wk;  out = WcatT + (long)2048 * EMB; ldi = 256; ct = 4; }
  else if (t < 1280) { t -= 1152; in = Wv;  out = WcatT + (long)2304 * EMB; ldi = 256; ct = 4; }
  else if (t < 2304) { t -= 1280; in = Wog; out = WcatT + (long)2560 * EMB; ldi = 2048; ct = 32; }
  else               { t -= 2304; in = Wout; out = WoutT;         ldi = 2048; ct = 32; }
  const long c0 = (long)(t % ct) * 64, r0 = (long)(t / ct) * 64;
  __shared__ float tl[64][65];
  const int lx = threadIdx.x & 63, ly = threadIdx.x >> 6;
  #pragma unroll
  for (int i = 0; i < 16; ++i)
    tl[ly + i * 4][lx] = in[(r0 + ly + i * 4) * ldi + c0 + lx];
  __syncthreads();
  #pragma unroll
  for (int i = 0; i < 16; ++i)
    out[(c0 + ly + i * 4) * EMB + r0 + lx] = f2h(tl[lx][ly + i * 4]);
}

// ---------------------------------------------------------------------------
// Tiled transpose + cast to f16 (f16 input path used for V^T).
// ---------------------------------------------------------------------------
template<typename TIN>
__global__ __launch_bounds__(256) void transpose_cast_kernel(
    const TIN* __restrict__ in, long ldi, _Float16* __restrict__ out, long ldo,
    long sIn, long sOut)
{
  __shared__ float t[64][65];
  const int lx = threadIdx.x & 63, ly = threadIdx.x >> 6;
  const long r0 = (long)blockIdx.y * 64, c0 = (long)blockIdx.x * 64;
  const TIN* ip = in + (long)blockIdx.z * sIn;
  _Float16* op = out + (long)blockIdx.z * sOut;
  #pragma unroll
  for (int i = 0; i < 16; ++i)
    t[ly + i * 4][lx] = (float)ip[(r0 + ly + i * 4) * ldi + c0 + lx];
  __syncthreads();
  #pragma unroll
  for (int i = 0; i < 16; ++i)
    op[(c0 + ly + i * 4) * ldo + r0 + lx] = f2h(t[lx][ly + i * 4]);
}

// ---------------------------------------------------------------------------
// f16 GEMM, 128x128 tile, BK=32, 4 waves (2x2), 3-deep prefetch, counted
// vmcnt; XOR-swizzled LDS (verified conflict-free R6); bijective XCD swizzle.
// ---------------------------------------------------------------------------
template<typename CT, int BM>
__global__ __launch_bounds__(256) void gemm_bt_kernel(
    const _Float16* __restrict__ Ag, const _Float16* __restrict__ Btg,
    CT* __restrict__ Cg, int K, int lda, int ldb, int ldc,
    long sA, long sB, long sC, int zdivB, int mtiles, int causal)
{
  constexpr int MR = BM / 32;
  __shared__ _Float16 As[3][BM * 32];
  __shared__ _Float16 Bs[3][128 * 32];
  const int tid = threadIdx.x;
  const int lane = tid & 63, wid = tid >> 6;
  const int cpx = gridDim.x >> 3;
  const int wg = ((int)blockIdx.x & 7) * cpx + ((int)blockIdx.x >> 3);
  const int m0 = (wg % mtiles) * BM;
  const int n0 = (wg / mtiles) * 128;
  const int z  = blockIdx.z;
  const _Float16* Ap = Ag + (long)z * sA + (long)m0 * lda;
  const _Float16* Bp = Btg + (long)(z / zdivB) * sB + (long)n0 * ldb;
  const int wr = wid >> 1, wc = wid & 1;
  const int lrow = lane & 15, kseg = lane >> 4;
  const int kl = causal ? ((m0 + BM < K) ? m0 + BM : K) : K;

  auto stage = [&](int b, int k0) {
    #pragma unroll
    for (int i = 0; i < BM / 64; ++i) {
      const int cbase = (i * 4 + wid) * 64;
      const int row = (cbase >> 2) + (lane >> 2);
      const int src = ((lane & 3) ^ ((row >> 1) & 3)) * 8;
      gload16(Ap + (long)row * lda + k0 + src, (char*)As[b] + cbase * 16);
    }
    #pragma unroll
    for (int i = 0; i < 2; ++i) {
      const int cbase = (i * 4 + wid) * 64;
      const int row = (cbase >> 2) + (lane >> 2);
      const int src = ((lane & 3) ^ ((row >> 1) & 3)) * 8;
      gload16(Bp + (long)row * ldb + k0 + src, (char*)Bs[b] + cbase * 16);
    }
  };

  const int nt = kl >> 5;
  f32x4 acc[MR][4] = {};
  stage(0, 0);
  if (nt > 1) stage(1, 32);
  for (int t = 0; t < nt; ++t) {
    if (t + 2 < nt) {
      stage((t + 2) % 3, (t + 2) * 32);
      asm volatile("s_waitcnt vmcnt(8)" ::: "memory");
    } else if (t + 1 < nt) {
      asm volatile("s_waitcnt vmcnt(4)" ::: "memory");
    } else {
      asm volatile("s_waitcnt vmcnt(0)" ::: "memory");
    }
    __builtin_amdgcn_s_barrier();
    __builtin_amdgcn_sched_barrier(0);
    const int buf = t % 3;
    f16x8 fa[MR], fb[4];
    #pragma unroll
    for (int m = 0; m < MR; ++m) {
      const int row = wr * (BM / 2) + m * 16 + lrow;
      fa[m] = *(const f16x8*)&As[buf][row * 32 + ((kseg ^ ((row >> 1) & 3)) << 3)];
    }
    #pragma unroll
    for (int n = 0; n < 4; ++n) {
      const int row = wc * 64 + n * 16 + lrow;
      fb[n] = *(const f16x8*)&Bs[buf][row * 32 + ((kseg ^ ((row >> 1) & 3)) << 3)];
    }
    #pragma unroll
    for (int m = 0; m < MR; ++m)
      #pragma unroll
      for (int n = 0; n < 4; ++n)
        acc[m][n] = __builtin_amdgcn_mfma_f32_16x16x32_f16(fa[m], fb[n], acc[m][n], 0, 0, 0);
    __builtin_amdgcn_s_barrier();
  }
  CT* Cp = Cg + (long)z * sC;
  #pragma unroll
  for (int m = 0; m < MR; ++m)
    #pragma unroll
    for (int n = 0; n < 4; ++n)
      #pragma unroll
      for (int i = 0; i < 4; ++i) {
        const int r = m0 + wr * (BM / 2) + m * 16 + kseg * 4 + i;  // row=(lane>>4)*4+i (m89)
        const int c = n0 + wc * 64 + n * 16 + lrow;                // col=lane&15
        Cp[(long)r * ldc + c] = (CT)acc[m][n][i];
      }
}

// ---------------------------------------------------------------------------
// Fused: x -> xh (f16 cast) + i/f gate projections.
// ---------------------------------------------------------------------------
__global__ __launch_bounds__(256) void proj_if_cast_kernel(
    const float* __restrict__ x, const float* __restrict__ Wi, const float* __restrict__ bi,
    const float* __restrict__ Wf, const float* __restrict__ bfg,
    _Float16* __restrict__ xh, float* __restrict__ ip, float* __restrict__ fp)
{
  const int tok = blockIdx.x;
  const int tid = threadIdx.x;
  const float* xr = x + (long)tok * EMB;
  float ai[8] = {}, af[8] = {};
  #pragma unroll
  for (int j = 0; j < 8; ++j) {
    const int e = tid + j * 256;
    const float xe = xr[e];
    xh[(long)tok * EMB + e] = f2h(xe);
    const float4* wi4 = (const float4*)(Wi + (long)e * 8);
    const float4* wf4 = (const float4*)(Wf + (long)e * 8);
    const float4 a0 = wi4[0], a1 = wi4[1], b0 = wf4[0], b1 = wf4[1];
    ai[0] += xe * a0.x; ai[1] += xe * a0.y; ai[2] += xe * a0.z; ai[3] += xe * a0.w;
    ai[4] += xe * a1.x; ai[5] += xe * a1.y; ai[6] += xe * a1.z; ai[7] += xe * a1.w;
    af[0] += xe * b0.x; af[1] += xe * b0.y; af[2] += xe * b0.z; af[3] += xe * b0.w;
    af[4] += xe * b1.x; af[5] += xe * b1.y; af[6] += xe * b1.z; af[7] += xe * b1.w;
  }
  #pragma unroll
  for (int hh = 0; hh < 8; ++hh)
    for (int off = 32; off; off >>= 1) {
      ai[hh] += __shfl_xor(ai[hh], off);
      af[hh] += __shfl_xor(af[hh], off);
    }
  __shared__ float red[4][16];
  const int lane = tid & 63, wid = tid >> 6;
  if (lane == 0) {
    #pragma unroll
    for (int hh = 0; hh < 8; ++hh) { red[wid][hh] = ai[hh]; red[wid][hh + 8] = af[hh]; }
  }
  __syncthreads();
  if (tid < 16) {
    const float v = red[0][tid] + red[1][tid] + red[2][tid] + red[3][tid];
    const int b = tok >> 10, s = tok & 1023;
    if (tid < 8) {
      const float zv = v + bi[tid];
      ip[(long)(b * NH_ + tid) * S_LEN + s] = 15.0f * tanhf(zv * (1.0f / 15.0f));
    } else {
      const int hh = tid - 8;
      const float zv = v + bfg[hh];
      fp[(long)(b * NH_ + hh) * S_LEN + s] = 15.0f * tanhf(zv * (1.0f / 15.0f));
    }
  }
}

// ---------------------------------------------------------------------------
// Per (b,h): logsigmoid, cumsum cf, a = i_pre - cf, running max m, vecM = cf+m.
// ---------------------------------------------------------------------------
__global__ __launch_bounds__(1024) void gates_kernel(
    const float* __restrict__ fp, const float* __restrict__ ip,
    float* __restrict__ aArr, float* __restrict__ mArr, float* __restrict__ vMArr)
{
  const int bh = blockIdx.x;
  const int s = threadIdx.x;
  __shared__ float sh[1024];
  const float f = fp[(long)bh * S_LEN + s];
  const float lsg = fminf(f, 0.0f) - log1pf(expf(-fabsf(f)));  // log_sigmoid
  float v = lsg;
  sh[s] = v; __syncthreads();
  for (int off = 1; off < 1024; off <<= 1) {
    const float o = (s >= off) ? sh[s - off] : 0.0f;
    __syncthreads();
    v += o; sh[s] = v;
    __syncthreads();
  }
  const float cf = v;
  const float a = ip[(long)bh * S_LEN + s] - cf;
  v = a;
  sh[s] = v; __syncthreads();
  for (int off = 1; off < 1024; off <<= 1) {
    const float o = (s >= off) ? sh[s - off] : -3.0e38f;
    __syncthreads();
    v = fmaxf(v, o); sh[s] = v;
    __syncthreads();
  }
  aArr[(long)bh * S_LEN + s] = a;
  mArr[(long)bh * S_LEN + s] = v;
  vMArr[(long)bh * S_LEN + s] = cf + v;
}

// ---------------------------------------------------------------------------
// Fused mLSTM attention, triangle-paired, QBLK=32, 512 threads / 8 waves.
// R11: same block tile and per-block load volume as R10 (the proven reuse
// economics) but split across 8 waves -> 2 waves/SIMD instead of 1, so loads
// and MFMA co-schedule across waves.  QK^T: wave w owns t-cols [16w,16w+16);
// PV: wave w owns d-cols [32w,32w+32).  K/V frags global->reg, pipelined.
// ---------------------------------------------------------------------------
__global__ __launch_bounds__(512) void att_fused_kernel(
    const _Float16* __restrict__ qkvo, const _Float16* __restrict__ vt,
    const float* __restrict__ aArr, const float* __restrict__ mArr,
    const float* __restrict__ vMArr, _Float16* __restrict__ hb)
{
  __shared__ _Float16 Qs[2][32 * 256];   // swizzled: 32 chunks/row, ^(row&7)
  __shared__ _Float16 Ws[2][32 * 128];   // swizzled: 16 chunks/row, ^((row&7)<<1)
  __shared__ float nsh[2][8][32];
  __shared__ float invs[2][32];
  const int tid = threadIdx.x;
  const int lane = tid & 63, wid = tid >> 6;     // 8 waves
  const int bh = blockIdx.y;
  const int b = bh >> 3, h = bh & 7;
  const int r0[2] = { (int)blockIdx.x * 32, (31 - (int)blockIdx.x) * 32 };
  const _Float16* Qg = qkvo + (long)(b * S_LEN) * NQKVO + h * DH_;
  const _Float16* Kg = qkvo + (long)(b * S_LEN) * NQKVO + 2048;
  const _Float16* Vt = vt + (long)b * DH_ * S_LEN;
  const float* aA = aArr + (long)bh * S_LEN;
  const float* mA = mArr + (long)bh * S_LEN;
  const int lrow = lane & 15, kseg = lane >> 4;
  const int tbase = 16 * wid;                    // QK t-slice per wave
  const int dbase = 32 * wid;                    // PV d-slice per wave

  // stage Q both subtiles: 2048 chunks of 16B, 4 iters x 512 lanes.
  #pragma unroll
  for (int i = 0; i < 4; ++i) {
    const int cbase = (i * 8 + wid) * 64;        // wave-uniform
    const int c = cbase + lane;
    const int sub = c >> 10, row = (c >> 5) & 31, slot = c & 31;
    gload16(Qg + (long)(r0[sub] + row) * NQKVO + (slot ^ (row & 7)) * 8,
            (char*)Qs + cbase * 16);
  }

  float m_s[2][2][4];
  #pragma unroll
  for (int sub = 0; sub < 2; ++sub)
    #pragma unroll
    for (int m = 0; m < 2; ++m)
      #pragma unroll
      for (int i = 0; i < 4; ++i)
        m_s[sub][m][i] = mA[r0[sub] + m * 16 + kseg * 4 + i];
  __syncthreads();   // Q staged (drains vmcnt)

  f32x4 hacc[2][2][2] = {};
  float nacc[2][2][4] = {};
  for (int n0 = 0; n0 <= r0[1]; n0 += 128) {
    // ---- QK^T: 1 K-frag per wave (16 t-cols), next-step reg prefetch ----
    f32x4 acc[2][2] = {};
    f16x8 fb, fbn;
    fb = *(const f16x8*)(Kg + (long)(n0 + tbase + lrow) * NQKVO + kseg * 8);
    #pragma unroll
    for (int k0 = 0; k0 < DH_; k0 += 32) {
      if (k0 + 32 < DH_)
        fbn = *(const f16x8*)(Kg + (long)(n0 + tbase + lrow) * NQKVO + k0 + 32 + kseg * 8);
      const int chunk = (k0 >> 3) + kseg;
      __builtin_amdgcn_s_setprio(1);
      #pragma unroll
      for (int sub = 0; sub < 2; ++sub) {
        if (n0 > r0[sub]) continue;
        #pragma unroll
        for (int m = 0; m < 2; ++m) {
          const int qrow = m * 16 + lrow;
          const f16x8 fa = *(const f16x8*)&Qs[sub][qrow * 256 + ((chunk ^ (qrow & 7)) << 3)];
          acc[sub][m] = __builtin_amdgcn_mfma_f32_16x16x32_f16(fa, fb, acc[sub][m], 0, 0, 0);
        }
      }
      __builtin_amdgcn_s_setprio(0);
      fb = fbn;
    }
    // ---- weighting -> Ws (swizzled), row-sum accumulation ----
    const float a_t = aA[n0 + tbase + lrow];
    #pragma unroll
    for (int sub = 0; sub < 2; ++sub) {
      if (n0 > r0[sub]) continue;
      #pragma unroll
      for (int m = 0; m < 2; ++m)
        #pragma unroll
        for (int i = 0; i < 4; ++i) {
          const int sr = m * 16 + kseg * 4 + i;     // local row 0..31
          const int t  = tbase + lrow;              // local col 0..127
          float w = 0.0f;
          if (n0 + t <= r0[sub] + sr)
            w = acc[sub][m][i] * 0.0625f * expf(a_t - m_s[sub][m][i]);
          nacc[sub][m][i] += w;
          Ws[sub][sr * 128 + (((t >> 3) ^ ((sr & 7) << 1)) << 3) + (t & 7)] = f2h(w);
        }
    }
    // ---- issue-early V loads for kt=0 ----
    f16x8 vb[2], vbn[2];
    #pragma unroll
    for (int n = 0; n < 2; ++n)
      vb[n] = *(const f16x8*)(Vt + (long)(dbase + n * 16 + lrow) * S_LEN + n0 + kseg * 8);
    __syncthreads();
    // ---- PV: Ws from LDS, V frags pipelined ----
    #pragma unroll
    for (int kt = 0; kt < 128; kt += 32) {
      if (kt + 32 < 128) {
        #pragma unroll
        for (int n = 0; n < 2; ++n)
          vbn[n] = *(const f16x8*)(Vt + (long)(dbase + n * 16 + lrow) * S_LEN + n0 + kt + 32 + kseg * 8);
      }
      const int chunk = (kt >> 3) + kseg;
      __builtin_amdgcn_s_setprio(1);
      #pragma unroll
      for (int sub = 0; sub < 2; ++sub) {
        if (n0 > r0[sub]) continue;
        #pragma unroll
        for (int m = 0; m < 2; ++m) {
          const int row = m * 16 + lrow;
          const f16x8 wa = *(const f16x8*)&Ws[sub][row * 128 + ((chunk ^ ((row & 7) << 1)) << 3)];
          #pragma unroll
          for (int n = 0; n < 2; ++n)
            hacc[sub][m][n] = __builtin_amdgcn_mfma_f32_16x16x32_f16(wa, vb[n], hacc[sub][m][n], 0, 0, 0);
        }
      }
      __builtin_amdgcn_s_setprio(0);
      vb[0] = vbn[0]; vb[1] = vbn[1];
    }
    __syncthreads();   // Ws reads done before next pass overwrites
  }
  // ---- row sums -> invn ----
  #pragma unroll
  for (int sub = 0; sub < 2; ++sub)
    #pragma unroll
    for (int m = 0; m < 2; ++m)
      #pragma unroll
      for (int i = 0; i < 4; ++i) {
        float v = nacc[sub][m][i];
        v += __shfl_xor(v, 1); v += __shfl_xor(v, 2);
        v += __shfl_xor(v, 4); v += __shfl_xor(v, 8);
        if (lrow == 0) nsh[sub][wid][m * 16 + kseg * 4 + i] = v;
      }
  __syncthreads();
  if (tid < 64) {
    const int sub = tid >> 5, sr = tid & 31;
    float tot = 0.0f;
    #pragma unroll
    for (int w = 0; w < 8; ++w) tot += nsh[sub][w][sr];
    const float vm = vMArr[(long)bh * S_LEN + r0[sub] + sr];
    const float vecN = fmaxf(fabsf(tot), expf(-vm));
    invs[sub][sr] = 1.0f / (vecN + 1e-6f);
  }
  __syncthreads();
  #pragma unroll
  for (int sub = 0; sub < 2; ++sub)
    #pragma unroll
    for (int m = 0; m < 2; ++m)
      #pragma unroll
      for (int n = 0; n < 2; ++n)
        #pragma unroll
        for (int i = 0; i < 4; ++i) {
          const int row = m * 16 + kseg * 4 + i;
          const int d = dbase + n * 16 + lrow;
          hb[((long)bh * S_LEN + r0[sub] + row) * DH_ + d] = f2h(hacc[sub][m][n][i] * invs[sub][row]);
        }
}

// ---------------------------------------------------------------------------
// One wave per (token, head) row: LN over DH=256 (f32), *gamma, *sigmoid(o).
// ---------------------------------------------------------------------------
__global__ __launch_bounds__(256) void ln_gate_kernel(
    const _Float16* __restrict__ hbuf,
    const _Float16* __restrict__ qkvo, const float* __restrict__ gamma,
    _Float16* __restrict__ u)
{
  const int wid = threadIdx.x >> 6, lane = threadIdx.x & 63;
  const int row = blockIdx.x * 4 + wid;   // row = tok*8 + h
  const int tok = row >> 3, h = row & 7;
  const int b = tok >> 10, s = tok & 1023;
  const int bh = b * NH_ + h;
  const f16x4 hv = *(const f16x4*)(hbuf + ((long)bh * S_LEN + s) * DH_ + lane * 4);
  const float v0 = (float)hv[0], v1 = (float)hv[1], v2 = (float)hv[2], v3 = (float)hv[3];
  float s1 = v0 + v1 + v2 + v3;
  float s2 = v0 * v0 + v1 * v1 + v2 * v2 + v3 * v3;
  for (int off = 32; off; off >>= 1) { s1 += __shfl_xor(s1, off); s2 += __shfl_xor(s2, off); }
  const float mu = s1 * (1.0f / 256.0f);
  const float var = s2 * (1.0f / 256.0f) - mu * mu;
  const float rs = rsqrtf(var + 1e-6f);
  const float4 g = *(const float4*)(gamma + h * DH_ + lane * 4);
  const f16x4 ov = *(const f16x4*)(qkvo + (long)tok * NQKVO + 2560 + h * DH_ + lane * 4);
  f16x4 res;
  res[0] = f2h((v0 - mu) * rs * g.x * (1.0f / (1.0f + expf(-(float)ov[0]))));
  res[1] = f2h((v1 - mu) * rs * g.y * (1.0f / (1.0f + expf(-(float)ov[1]))));
  res[2] = f2h((v2 - mu) * rs * g.z * (1.0f / (1.0f + expf(-(float)ov[2]))));
  res[3] = f2h((v3 - mu) * rs * g.w * (1.0f / (1.0f + expf(-(float)ov[3]))));
  *(f16x4*)(u + (long)tok * EMB + h * DH_ + lane * 4) = res;
}

// ---------------------------------------------------------------------------
extern "C" void kernel_launch(void* const* d_in, const int* in_sizes, int n_in,
                              void* d_out, int out_size, void* d_ws, size_t ws_size,
                              hipStream_t stream)
{
  (void)in_sizes; (void)n_in; (void)out_size; (void)ws_size;
  const float* x     = (const float*)d_in[0];
  const float* Wq    = (const float*)d_in[1];
  const float* Wk    = (const float*)d_in[2];
  const float* Wv    = (const float*)d_in[3];
  const float* Wog   = (const float*)d_in[4];
  const float* Wi    = (const float*)d_in[5];
  const float* bi    = (const float*)d_in[6];
  const float* Wf    = (const float*)d_in[7];
  const float* bfg   = (const float*)d_in[8];
  const float* gamma = (const float*)d_in[9];
  const float* Wout  = (const float*)d_in[10];

  char* base = (char*)d_ws;
  size_t off = 0;
  auto take = [&](size_t bytes) -> char* {
    char* p = base + off;
    off += (bytes + 255) & ~(size_t)255;
    return p;
  };
  _Float16* xh    = (_Float16*)take((size_t)TOKENS * EMB * 2);        //  8 MB
  _Float16* WcatT = (_Float16*)take((size_t)NQKVO * EMB * 2);         // 19 MB
  _Float16* WoutT = (_Float16*)take((size_t)EMB * EMB * 2);           //  8 MB
  _Float16* qkvo  = (_Float16*)take((size_t)TOKENS * NQKVO * 2);      // 19 MB
  _Float16* vt    = (_Float16*)take((size_t)2 * DH_ * S_LEN * 2);     //  1 MB
  _Float16* hb    = (_Float16*)take((size_t)NBH * S_LEN * DH_ * 2);   //  8 MB
  float*    ip    = (float*)take((size_t)NBH * S_LEN * 4);
  float*    fp    = (float*)take((size_t)NBH * S_LEN * 4);
  float*    aA    = (float*)take((size_t)NBH * S_LEN * 4);
  float*    mA    = (float*)take((size_t)NBH * S_LEN * 4);
  float*    vM    = (float*)take((size_t)NBH * S_LEN * 4);
  _Float16* ub    = xh;   // xh dead after QKVO GEMM
  float*    y     = (float*)d_out;

  const dim3 blk(256);
  // --- prep: fused x-cast + i/f projections; all weight transposes ---
  proj_if_cast_kernel<<<dim3(TOKENS), blk, 0, stream>>>(x, Wi, bi, Wf, bfg, xh, ip, fp);
  transpose_all_kernel<<<dim3(3328), blk, 0, stream>>>(Wq, Wk, Wv, Wog, Wout, WcatT, WoutT);
  // --- fused QKVO projection: [2048,4608] = xh @ WcatT^T (576 blocks) ---
  gemm_bt_kernel<_Float16, 128><<<dim3(36 * 16), blk, 0, stream>>>(
      xh, WcatT, qkvo, EMB, EMB, EMB, NQKVO, 0L, 0L, 0L, 1, 16, 0);
  // --- V^T per batch ---
  transpose_cast_kernel<_Float16><<<dim3(4, 16, 2), blk, 0, stream>>>(
      qkvo + 2304, NQKVO, vt, S_LEN, (long)S_LEN * NQKVO, (long)DH_ * S_LEN);
  // --- gates ---
  gates_kernel<<<dim3(NBH), dim3(1024), 0, stream>>>(fp, ip, aA, mA, vM);
  // --- fused mLSTM backend (QBLK=32 pairs, 256 blocks x 8 waves) ---
  att_fused_kernel<<<dim3(16, NBH), dim3(512), 0, stream>>>(qkvo, vt, aA, mA, vM, hb);
  // --- layernorm + output gate ---
  ln_gate_kernel<<<dim3(TOKENS * NH_ / 4), blk, 0, stream>>>(hb, qkvo, gamma, ub);
  // --- output projection (16 m x 16 n, 128x128 tiles) ---
  gemm_bt_kernel<float, 128><<<dim3(16 * 16), blk, 0, stream>>>(
      ub, WoutT, y, EMB, EMB, EMB, EMB, 0L, 0L, 0L, 1, 16, 0);
}

// Round 12
// 179.582 us; speedup vs baseline: 1.5553x; 1.0431x over previous
//
#include <hip/hip_runtime.h>
#include <math.h>

#define S_LEN  1024
#define EMB    2048
#define NH_    8
#define DH_    256
#define TOKENS 2048   // B*S
#define NBH    16     // B*NH
#define NQKVO  4608   // 2048 q | 256 k | 256 v | 2048 o

typedef __attribute__((ext_vector_type(4))) float    f32x4;
typedef __attribute__((ext_vector_type(8))) _Float16 f16x8;
typedef __attribute__((ext_vector_type(4))) _Float16 f16x4;

__device__ __forceinline__ _Float16 f2h(float f) { return (_Float16)f; }

// async global->LDS, 16B per lane; LDS dest = wave-uniform base + lane*16
__device__ __forceinline__ void gload16(const void* g, void* l) {
  __builtin_amdgcn_global_load_lds(
      (const __attribute__((address_space(1))) void*)g,
      (__attribute__((address_space(3))) void*)l, 16, 0, 0);
}

// ---------------------------------------------------------------------------
// Merged prep: blocks [0,2048): x->xh cast + i/f gate projections;
// blocks [2048,5376): weight transposes (Wq,Wk,Wv,Wog->WcatT; Wout->WoutT).
// One launch; x-stream and W-stream interleave across CUs.
// ---------------------------------------------------------------------------
__global__ __launch_bounds__(256) void prep_kernel(
    const float* __restrict__ x, const float* __restrict__ Wi, const float* __restrict__ bi,
    const float* __restrict__ Wf, const float* __restrict__ bfg,
    const float* __restrict__ Wq, const float* __restrict__ Wk,
    const float* __restrict__ Wv, const float* __restrict__ Wog,
    const float* __restrict__ Wout,
    _Float16* __restrict__ xh, float* __restrict__ ip, float* __restrict__ fp,
    _Float16* __restrict__ WcatT, _Float16* __restrict__ WoutT)
{
  __shared__ float shmem[64][65];
  int t = blockIdx.x;
  const int tid = threadIdx.x;
  if (t < TOKENS) {
    // ---- proj_if_cast ----
    const int tok = t;
    const float* xr = x + (long)tok * EMB;
    float ai[8] = {}, af[8] = {};
    #pragma unroll
    for (int j = 0; j < 8; ++j) {
      const int e = tid + j * 256;
      const float xe = xr[e];
      xh[(long)tok * EMB + e] = f2h(xe);
      const float4* wi4 = (const float4*)(Wi + (long)e * 8);
      const float4* wf4 = (const float4*)(Wf + (long)e * 8);
      const float4 a0 = wi4[0], a1 = wi4[1], b0 = wf4[0], b1 = wf4[1];
      ai[0] += xe * a0.x; ai[1] += xe * a0.y; ai[2] += xe * a0.z; ai[3] += xe * a0.w;
      ai[4] += xe * a1.x; ai[5] += xe * a1.y; ai[6] += xe * a1.z; ai[7] += xe * a1.w;
      af[0] += xe * b0.x; af[1] += xe * b0.y; af[2] += xe * b0.z; af[3] += xe * b0.w;
      af[4] += xe * b1.x; af[5] += xe * b1.y; af[6] += xe * b1.z; af[7] += xe * b1.w;
    }
    #pragma unroll
    for (int hh = 0; hh < 8; ++hh)
      for (int off = 32; off; off >>= 1) {
        ai[hh] += __shfl_xor(ai[hh], off);
        af[hh] += __shfl_xor(af[hh], off);
      }
    float (*red)[16] = (float(*)[16])shmem;
    const int lane = tid & 63, wid = tid >> 6;
    if (lane == 0) {
      #pragma unroll
      for (int hh = 0; hh < 8; ++hh) { red[wid][hh] = ai[hh]; red[wid][hh + 8] = af[hh]; }
    }
    __syncthreads();
    if (tid < 16) {
      const float v = red[0][tid] + red[1][tid] + red[2][tid] + red[3][tid];
      const int b = tok >> 10, s = tok & 1023;
      if (tid < 8) {
        const float zv = v + bi[tid];
        ip[(long)(b * NH_ + tid) * S_LEN + s] = 15.0f * tanhf(zv * (1.0f / 15.0f));
      } else {
        const int hh = tid - 8;
        const float zv = v + bfg[hh];
        fp[(long)(b * NH_ + hh) * S_LEN + s] = 15.0f * tanhf(zv * (1.0f / 15.0f));
      }
    }
  } else {
    // ---- weight transposes ----
    t -= TOKENS;
    const float* in; _Float16* out; int ldi, ct;
    if (t < 1024)      { in = Wq;   out = WcatT;                    ldi = 2048; ct = 32; }
    else if (t < 1152) { t -= 1024; in = Wk;  out = WcatT + (long)2048 * EMB; ldi = 256; ct = 4; }
    else if (t < 1280) { t -= 1152; in = Wv;  out = WcatT + (long)2304 * EMB; ldi = 256; ct = 4; }
    else if (t < 2304) { t -= 1280; in = Wog; out = WcatT + (long)2560 * EMB; ldi = 2048; ct = 32; }
    else               { t -= 2304; in = Wout; out = WoutT;         ldi = 2048; ct = 32; }
    const long c0 = (long)(t % ct) * 64, r0 = (long)(t / ct) * 64;
    const int lx = tid & 63, ly = tid >> 6;
    #pragma unroll
    for (int i = 0; i < 16; ++i)
      shmem[ly + i * 4][lx] = in[(r0 + ly + i * 4) * ldi + c0 + lx];
    __syncthreads();
    #pragma unroll
    for (int i = 0; i < 16; ++i)
      out[(c0 + ly + i * 4) * EMB + r0 + lx] = f2h(shmem[lx][ly + i * 4]);
  }
}

// ---------------------------------------------------------------------------
// Tiled transpose + cast to f16 (f16 input path used for V^T).
// ---------------------------------------------------------------------------
template<typename TIN>
__global__ __launch_bounds__(256) void transpose_cast_kernel(
    const TIN* __restrict__ in, long ldi, _Float16* __restrict__ out, long ldo,
    long sIn, long sOut)
{
  __shared__ float t[64][65];
  const int lx = threadIdx.x & 63, ly = threadIdx.x >> 6;
  const long r0 = (long)blockIdx.y * 64, c0 = (long)blockIdx.x * 64;
  const TIN* ip = in + (long)blockIdx.z * sIn;
  _Float16* op = out + (long)blockIdx.z * sOut;
  #pragma unroll
  for (int i = 0; i < 16; ++i)
    t[ly + i * 4][lx] = (float)ip[(r0 + ly + i * 4) * ldi + c0 + lx];
  __syncthreads();
  #pragma unroll
  for (int i = 0; i < 16; ++i)
    op[(c0 + ly + i * 4) * ldo + r0 + lx] = f2h(t[lx][ly + i * 4]);
}

// ---------------------------------------------------------------------------
// f16 GEMM, BMx128 tile, BK=32, 4 waves, 3-deep prefetch, counted vmcnt
// (= 2L / L / 0 where L = BM/64+2 loads per thread per stage); XOR-swizzled
// LDS (verified conflict-free R6); bijective XCD swizzle.
// BM=128: 16 MFMA/step/wave, 49KB LDS (3 blocks/CU).
// BM=64:  8 MFMA/step/wave, 36KB LDS (4 blocks/CU) — for small grids (R12).
// ---------------------------------------------------------------------------
template<typename CT, int BM>
__global__ __launch_bounds__(256) void gemm_bt_kernel(
    const _Float16* __restrict__ Ag, const _Float16* __restrict__ Btg,
    CT* __restrict__ Cg, int K, int lda, int ldb, int ldc,
    long sA, long sB, long sC, int zdivB, int mtiles, int causal)
{
  constexpr int MR = BM / 32;
  __shared__ _Float16 As[3][BM * 32];
  __shared__ _Float16 Bs[3][128 * 32];
  const int tid = threadIdx.x;
  const int lane = tid & 63, wid = tid >> 6;
  const int cpx = gridDim.x >> 3;
  const int wg = ((int)blockIdx.x & 7) * cpx + ((int)blockIdx.x >> 3);
  const int m0 = (wg % mtiles) * BM;
  const int n0 = (wg / mtiles) * 128;
  const int z  = blockIdx.z;
  const _Float16* Ap = Ag + (long)z * sA + (long)m0 * lda;
  const _Float16* Bp = Btg + (long)(z / zdivB) * sB + (long)n0 * ldb;
  const int wr = wid >> 1, wc = wid & 1;
  const int lrow = lane & 15, kseg = lane >> 4;
  const int kl = causal ? ((m0 + BM < K) ? m0 + BM : K) : K;

  auto stage = [&](int b, int k0) {
    #pragma unroll
    for (int i = 0; i < BM / 64; ++i) {
      const int cbase = (i * 4 + wid) * 64;
      const int row = (cbase >> 2) + (lane >> 2);
      const int src = ((lane & 3) ^ ((row >> 1) & 3)) * 8;
      gload16(Ap + (long)row * lda + k0 + src, (char*)As[b] + cbase * 16);
    }
    #pragma unroll
    for (int i = 0; i < 2; ++i) {
      const int cbase = (i * 4 + wid) * 64;
      const int row = (cbase >> 2) + (lane >> 2);
      const int src = ((lane & 3) ^ ((row >> 1) & 3)) * 8;
      gload16(Bp + (long)row * ldb + k0 + src, (char*)Bs[b] + cbase * 16);
    }
  };

  const int nt = kl >> 5;
  f32x4 acc[MR][4] = {};
  stage(0, 0);
  if (nt > 1) stage(1, 32);
  for (int t = 0; t < nt; ++t) {
    if (t + 2 < nt) {
      stage((t + 2) % 3, (t + 2) * 32);
      if constexpr (BM == 128) asm volatile("s_waitcnt vmcnt(8)" ::: "memory");
      else                     asm volatile("s_waitcnt vmcnt(6)" ::: "memory");
    } else if (t + 1 < nt) {
      if constexpr (BM == 128) asm volatile("s_waitcnt vmcnt(4)" ::: "memory");
      else                     asm volatile("s_waitcnt vmcnt(3)" ::: "memory");
    } else {
      asm volatile("s_waitcnt vmcnt(0)" ::: "memory");
    }
    __builtin_amdgcn_s_barrier();
    __builtin_amdgcn_sched_barrier(0);
    const int buf = t % 3;
    f16x8 fa[MR], fb[4];
    #pragma unroll
    for (int m = 0; m < MR; ++m) {
      const int row = wr * (BM / 2) + m * 16 + lrow;
      fa[m] = *(const f16x8*)&As[buf][row * 32 + ((kseg ^ ((row >> 1) & 3)) << 3)];
    }
    #pragma unroll
    for (int n = 0; n < 4; ++n) {
      const int row = wc * 64 + n * 16 + lrow;
      fb[n] = *(const f16x8*)&Bs[buf][row * 32 + ((kseg ^ ((row >> 1) & 3)) << 3)];
    }
    #pragma unroll
    for (int m = 0; m < MR; ++m)
      #pragma unroll
      for (int n = 0; n < 4; ++n)
        acc[m][n] = __builtin_amdgcn_mfma_f32_16x16x32_f16(fa[m], fb[n], acc[m][n], 0, 0, 0);
    __builtin_amdgcn_s_barrier();
  }
  CT* Cp = Cg + (long)z * sC;
  #pragma unroll
  for (int m = 0; m < MR; ++m)
    #pragma unroll
    for (int n = 0; n < 4; ++n)
      #pragma unroll
      for (int i = 0; i < 4; ++i) {
        const int r = m0 + wr * (BM / 2) + m * 16 + kseg * 4 + i;  // row=(lane>>4)*4+i (m89)
        const int c = n0 + wc * 64 + n * 16 + lrow;                // col=lane&15
        Cp[(long)r * ldc + c] = (CT)acc[m][n][i];
      }
}

// ---------------------------------------------------------------------------
// Per (b,h): logsigmoid, cumsum cf, a = i_pre - cf, running max m, vecM = cf+m.
// ---------------------------------------------------------------------------
__global__ __launch_bounds__(1024) void gates_kernel(
    const float* __restrict__ fp, const float* __restrict__ ip,
    float* __restrict__ aArr, float* __restrict__ mArr, float* __restrict__ vMArr)
{
  const int bh = blockIdx.x;
  const int s = threadIdx.x;
  __shared__ float sh[1024];
  const float f = fp[(long)bh * S_LEN + s];
  const float lsg = fminf(f, 0.0f) - log1pf(expf(-fabsf(f)));  // log_sigmoid
  float v = lsg;
  sh[s] = v; __syncthreads();
  for (int off = 1; off < 1024; off <<= 1) {
    const float o = (s >= off) ? sh[s - off] : 0.0f;
    __syncthreads();
    v += o; sh[s] = v;
    __syncthreads();
  }
  const float cf = v;
  const float a = ip[(long)bh * S_LEN + s] - cf;
  v = a;
  sh[s] = v; __syncthreads();
  for (int off = 1; off < 1024; off <<= 1) {
    const float o = (s >= off) ? sh[s - off] : -3.0e38f;
    __syncthreads();
    v = fmaxf(v, o); sh[s] = v;
    __syncthreads();
  }
  aArr[(long)bh * S_LEN + s] = a;
  mArr[(long)bh * S_LEN + s] = v;
  vMArr[(long)bh * S_LEN + s] = cf + v;
}

// ---------------------------------------------------------------------------
// Fused mLSTM attention, triangle-paired, QBLK=32, 512 threads / 8 waves
// (R11 config: 2 waves/SIMD, K/V frags global->reg with reg pipelining).
// ---------------------------------------------------------------------------
__global__ __launch_bounds__(512) void att_fused_kernel(
    const _Float16* __restrict__ qkvo, const _Float16* __restrict__ vt,
    const float* __restrict__ aArr, const float* __restrict__ mArr,
    const float* __restrict__ vMArr, _Float16* __restrict__ hb)
{
  __shared__ _Float16 Qs[2][32 * 256];   // swizzled: 32 chunks/row, ^(row&7)
  __shared__ _Float16 Ws[2][32 * 128];   // swizzled: 16 chunks/row, ^((row&7)<<1)
  __shared__ float nsh[2][8][32];
  __shared__ float invs[2][32];
  const int tid = threadIdx.x;
  const int lane = tid & 63, wid = tid >> 6;     // 8 waves
  const int bh = blockIdx.y;
  const int b = bh >> 3, h = bh & 7;
  const int r0[2] = { (int)blockIdx.x * 32, (31 - (int)blockIdx.x) * 32 };
  const _Float16* Qg = qkvo + (long)(b * S_LEN) * NQKVO + h * DH_;
  const _Float16* Kg = qkvo + (long)(b * S_LEN) * NQKVO + 2048;
  const _Float16* Vt = vt + (long)b * DH_ * S_LEN;
  const float* aA = aArr + (long)bh * S_LEN;
  const float* mA = mArr + (long)bh * S_LEN;
  const int lrow = lane & 15, kseg = lane >> 4;
  const int tbase = 16 * wid;                    // QK t-slice per wave
  const int dbase = 32 * wid;                    // PV d-slice per wave

  #pragma unroll
  for (int i = 0; i < 4; ++i) {
    const int cbase = (i * 8 + wid) * 64;        // wave-uniform
    const int c = cbase + lane;
    const int sub = c >> 10, row = (c >> 5) & 31, slot = c & 31;
    gload16(Qg + (long)(r0[sub] + row) * NQKVO + (slot ^ (row & 7)) * 8,
            (char*)Qs + cbase * 16);
  }

  float m_s[2][2][4];
  #pragma unroll
  for (int sub = 0; sub < 2; ++sub)
    #pragma unroll
    for (int m = 0; m < 2; ++m)
      #pragma unroll
      for (int i = 0; i < 4; ++i)
        m_s[sub][m][i] = mA[r0[sub] + m * 16 + kseg * 4 + i];
  __syncthreads();   // Q staged (drains vmcnt)

  f32x4 hacc[2][2][2] = {};
  float nacc[2][2][4] = {};
  for (int n0 = 0; n0 <= r0[1]; n0 += 128) {
    // ---- QK^T: 1 K-frag per wave (16 t-cols), next-step reg prefetch ----
    f32x4 acc[2][2] = {};
    f16x8 fb, fbn;
    fb = *(const f16x8*)(Kg + (long)(n0 + tbase + lrow) * NQKVO + kseg * 8);
    #pragma unroll
    for (int k0 = 0; k0 < DH_; k0 += 32) {
      if (k0 + 32 < DH_)
        fbn = *(const f16x8*)(Kg + (long)(n0 + tbase + lrow) * NQKVO + k0 + 32 + kseg * 8);
      const int chunk = (k0 >> 3) + kseg;
      __builtin_amdgcn_s_setprio(1);
      #pragma unroll
      for (int sub = 0; sub < 2; ++sub) {
        if (n0 > r0[sub]) continue;
        #pragma unroll
        for (int m = 0; m < 2; ++m) {
          const int qrow = m * 16 + lrow;
          const f16x8 fa = *(const f16x8*)&Qs[sub][qrow * 256 + ((chunk ^ (qrow & 7)) << 3)];
          acc[sub][m] = __builtin_amdgcn_mfma_f32_16x16x32_f16(fa, fb, acc[sub][m], 0, 0, 0);
        }
      }
      __builtin_amdgcn_s_setprio(0);
      fb = fbn;
    }
    // ---- weighting -> Ws (swizzled), row-sum accumulation ----
    const float a_t = aA[n0 + tbase + lrow];
    #pragma unroll
    for (int sub = 0; sub < 2; ++sub) {
      if (n0 > r0[sub]) continue;
      #pragma unroll
      for (int m = 0; m < 2; ++m)
        #pragma unroll
        for (int i = 0; i < 4; ++i) {
          const int sr = m * 16 + kseg * 4 + i;     // local row 0..31
          const int t  = tbase + lrow;              // local col 0..127
          float w = 0.0f;
          if (n0 + t <= r0[sub] + sr)
            w = acc[sub][m][i] * 0.0625f * expf(a_t - m_s[sub][m][i]);
          nacc[sub][m][i] += w;
          Ws[sub][sr * 128 + (((t >> 3) ^ ((sr & 7) << 1)) << 3) + (t & 7)] = f2h(w);
        }
    }
    // ---- issue-early V loads for kt=0 ----
    f16x8 vb[2], vbn[2];
    #pragma unroll
    for (int n = 0; n < 2; ++n)
      vb[n] = *(const f16x8*)(Vt + (long)(dbase + n * 16 + lrow) * S_LEN + n0 + kseg * 8);
    __syncthreads();
    // ---- PV: Ws from LDS, V frags pipelined ----
    #pragma unroll
    for (int kt = 0; kt < 128; kt += 32) {
      if (kt + 32 < 128) {
        #pragma unroll
        for (int n = 0; n < 2; ++n)
          vbn[n] = *(const f16x8*)(Vt + (long)(dbase + n * 16 + lrow) * S_LEN + n0 + kt + 32 + kseg * 8);
      }
      const int chunk = (kt >> 3) + kseg;
      __builtin_amdgcn_s_setprio(1);
      #pragma unroll
      for (int sub = 0; sub < 2; ++sub) {
        if (n0 > r0[sub]) continue;
        #pragma unroll
        for (int m = 0; m < 2; ++m) {
          const int row = m * 16 + lrow;
          const f16x8 wa = *(const f16x8*)&Ws[sub][row * 128 + ((chunk ^ ((row & 7) << 1)) << 3)];
          #pragma unroll
          for (int n = 0; n < 2; ++n)
            hacc[sub][m][n] = __builtin_amdgcn_mfma_f32_16x16x32_f16(wa, vb[n], hacc[sub][m][n], 0, 0, 0);
        }
      }
      __builtin_amdgcn_s_setprio(0);
      vb[0] = vbn[0]; vb[1] = vbn[1];
    }
    __syncthreads();   // Ws reads done before next pass overwrites
  }
  // ---- row sums -> invn ----
  #pragma unroll
  for (int sub = 0; sub < 2; ++sub)
    #pragma unroll
    for (int m = 0; m < 2; ++m)
      #pragma unroll
      for (int i = 0; i < 4; ++i) {
        float v = nacc[sub][m][i];
        v += __shfl_xor(v, 1); v += __shfl_xor(v, 2);
        v += __shfl_xor(v, 4); v += __shfl_xor(v, 8);
        if (lrow == 0) nsh[sub][wid][m * 16 + kseg * 4 + i] = v;
      }
  __syncthreads();
  if (tid < 64) {
    const int sub = tid >> 5, sr = tid & 31;
    float tot = 0.0f;
    #pragma unroll
    for (int w = 0; w < 8; ++w) tot += nsh[sub][w][sr];
    const float vm = vMArr[(long)bh * S_LEN + r0[sub] + sr];
    const float vecN = fmaxf(fabsf(tot), expf(-vm));
    invs[sub][sr] = 1.0f / (vecN + 1e-6f);
  }
  __syncthreads();
  #pragma unroll
  for (int sub = 0; sub < 2; ++sub)
    #pragma unroll
    for (int m = 0; m < 2; ++m)
      #pragma unroll
      for (int n = 0; n < 2; ++n)
        #pragma unroll
        for (int i = 0; i < 4; ++i) {
          const int row = m * 16 + kseg * 4 + i;
          const int d = dbase + n * 16 + lrow;
          hb[((long)bh * S_LEN + r0[sub] + row) * DH_ + d] = f2h(hacc[sub][m][n][i] * invs[sub][row]);
        }
}

// ---------------------------------------------------------------------------
// One wave per (token, head) row: LN over DH=256 (f32), *gamma, *sigmoid(o).
// ---------------------------------------------------------------------------
__global__ __launch_bounds__(256) void ln_gate_kernel(
    const _Float16* __restrict__ hbuf,
    const _Float16* __restrict__ qkvo, const float* __restrict__ gamma,
    _Float16* __restrict__ u)
{
  const int wid = threadIdx.x >> 6, lane = threadIdx.x & 63;
  const int row = blockIdx.x * 4 + wid;   // row = tok*8 + h
  const int tok = row >> 3, h = row & 7;
  const int b = tok >> 10, s = tok & 1023;
  const int bh = b * NH_ + h;
  const f16x4 hv = *(const f16x4*)(hbuf + ((long)bh * S_LEN + s) * DH_ + lane * 4);
  const float v0 = (float)hv[0], v1 = (float)hv[1], v2 = (float)hv[2], v3 = (float)hv[3];
  float s1 = v0 + v1 + v2 + v3;
  float s2 = v0 * v0 + v1 * v1 + v2 * v2 + v3 * v3;
  for (int off = 32; off; off >>= 1) { s1 += __shfl_xor(s1, off); s2 += __shfl_xor(s2, off); }
  const float mu = s1 * (1.0f / 256.0f);
  const float var = s2 * (1.0f / 256.0f) - mu * mu;
  const float rs = rsqrtf(var + 1e-6f);
  const float4 g = *(const float4*)(gamma + h * DH_ + lane * 4);
  const f16x4 ov = *(const f16x4*)(qkvo + (long)tok * NQKVO + 2560 + h * DH_ + lane * 4);
  f16x4 res;
  res[0] = f2h((v0 - mu) * rs * g.x * (1.0f / (1.0f + expf(-(float)ov[0]))));
  res[1] = f2h((v1 - mu) * rs * g.y * (1.0f / (1.0f + expf(-(float)ov[1]))));
  res[2] = f2h((v2 - mu) * rs * g.z * (1.0f / (1.0f + expf(-(float)ov[2]))));
  res[3] = f2h((v3 - mu) * rs * g.w * (1.0f / (1.0f + expf(-(float)ov[3]))));
  *(f16x4*)(u + (long)tok * EMB + h * DH_ + lane * 4) = res;
}

// ---------------------------------------------------------------------------
extern "C" void kernel_launch(void* const* d_in, const int* in_sizes, int n_in,
                              void* d_out, int out_size, void* d_ws, size_t ws_size,
                              hipStream_t stream)
{
  (void)in_sizes; (void)n_in; (void)out_size; (void)ws_size;
  const float* x     = (const float*)d_in[0];
  const float* Wq    = (const float*)d_in[1];
  const float* Wk    = (const float*)d_in[2];
  const float* Wv    = (const float*)d_in[3];
  const float* Wog   = (const float*)d_in[4];
  const float* Wi    = (const float*)d_in[5];
  const float* bi    = (const float*)d_in[6];
  const float* Wf    = (const float*)d_in[7];
  const float* bfg   = (const float*)d_in[8];
  const float* gamma = (const float*)d_in[9];
  const float* Wout  = (const float*)d_in[10];

  char* base = (char*)d_ws;
  size_t off = 0;
  auto take = [&](size_t bytes) -> char* {
    char* p = base + off;
    off += (bytes + 255) & ~(size_t)255;
    return p;
  };
  _Float16* xh    = (_Float16*)take((size_t)TOKENS * EMB * 2);        //  8 MB
  _Float16* WcatT = (_Float16*)take((size_t)NQKVO * EMB * 2);         // 19 MB
  _Float16* WoutT = (_Float16*)take((size_t)EMB * EMB * 2);           //  8 MB
  _Float16* qkvo  = (_Float16*)take((size_t)TOKENS * NQKVO * 2);      // 19 MB
  _Float16* vt    = (_Float16*)take((size_t)2 * DH_ * S_LEN * 2);     //  1 MB
  _Float16* hb    = (_Float16*)take((size_t)NBH * S_LEN * DH_ * 2);   //  8 MB
  float*    ip    = (float*)take((size_t)NBH * S_LEN * 4);
  float*    fp    = (float*)take((size_t)NBH * S_LEN * 4);
  float*    aA    = (float*)take((size_t)NBH * S_LEN * 4);
  float*    mA    = (float*)take((size_t)NBH * S_LEN * 4);
  float*    vM    = (float*)take((size_t)NBH * S_LEN * 4);
  _Float16* ub    = xh;   // xh dead after QKVO GEMM
  float*    y     = (float*)d_out;

  const dim3 blk(256);
  // --- merged prep: x cast + i/f projections + all weight transposes ---
  prep_kernel<<<dim3(TOKENS + 3328), blk, 0, stream>>>(
      x, Wi, bi, Wf, bfg, Wq, Wk, Wv, Wog, Wout, xh, ip, fp, WcatT, WoutT);
  // --- fused QKVO projection: [2048,4608] = xh @ WcatT^T (576 blocks) ---
  gemm_bt_kernel<_Float16, 128><<<dim3(36 * 16), blk, 0, stream>>>(
      xh, WcatT, qkvo, EMB, EMB, EMB, NQKVO, 0L, 0L, 0L, 1, 16, 0);
  // --- V^T per batch ---
  transpose_cast_kernel<_Float16><<<dim3(4, 16, 2), blk, 0, stream>>>(
      qkvo + 2304, NQKVO, vt, S_LEN, (long)S_LEN * NQKVO, (long)DH_ * S_LEN);
  // --- gates ---
  gates_kernel<<<dim3(NBH), dim3(1024), 0, stream>>>(fp, ip, aA, mA, vM);
  // --- fused mLSTM backend (QBLK=32 pairs, 256 blocks x 8 waves) ---
  att_fused_kernel<<<dim3(16, NBH), dim3(512), 0, stream>>>(qkvo, vt, aA, mA, vM, hb);
  // --- layernorm + output gate ---
  ln_gate_kernel<<<dim3(TOKENS * NH_ / 4), blk, 0, stream>>>(hb, qkvo, gamma, ub);
  // --- output projection: BM=64, 512 blocks -> 4 blocks/CU (R12) ---
  gemm_bt_kernel<float, 64><<<dim3(32 * 16), blk, 0, stream>>>(
      ub, WoutT, y, EMB, EMB, EMB, EMB, 0L, 0L, 0L, 1, 32, 0);
}